// Round 1
// baseline (11681.500 us; speedup 1.0000x reference)
//
#include <hip/hip_runtime.h>
#include <math.h>

// ---------------------------------------------------------------------------
// VQ-VAE forward, f32, accuracy-first.
// Sizes: B=4096, G=20000, D1=2048, D2=1024, D3=512, K=8192.
// Outputs: [loss(1)] [x_recon(4096*20000)] [quantized_st(4096*512)]
// ---------------------------------------------------------------------------

#define GEMM_BM 64
#define GEMM_BN 64
#define GEMM_BK 16

// C[M,N] = act(A[M,K] @ B[K,N] + bias[N]); ACT: 0=none, 1=tanh.
// Accuracy: per-thread f32 chunk accumulators flushed into f64 totals every
// 4 K-tiles (64 K-terms) -> accumulation error ~1e-7 instead of ~4e-6.
// Requires M%64==0, K%16==0 (true for all calls). N edge is guarded.
template<int ACT>
__global__ __launch_bounds__(256) void gemm_f32(
    const float* __restrict__ A, const float* __restrict__ B,
    const float* __restrict__ bias, float* __restrict__ C,
    int M, int N, int K)
{
    __shared__ float As[GEMM_BK][GEMM_BM];
    __shared__ float Bs[GEMM_BK][GEMM_BN];
    const int tid = threadIdx.x;
    const int tx = tid & 15;
    const int ty = tid >> 4;
    const int bm = blockIdx.y * GEMM_BM;
    const int bn = blockIdx.x * GEMM_BN;

    const int a_r = tid >> 2;         // 0..63 row within A tile
    const int a_k = (tid & 3) << 2;   // 0,4,8,12 k within tile
    const int b_k = tid >> 4;         // 0..15 k row of B tile
    const int b_n = (tid & 15) << 2;  // 0..60 col within tile

    float  accc[4][4];
    double acct[4][4];
    #pragma unroll
    for (int i = 0; i < 4; ++i) {
        #pragma unroll
        for (int j = 0; j < 4; ++j) { accc[i][j] = 0.f; acct[i][j] = 0.0; }
    }

    const float* Arow = A + (size_t)(bm + a_r) * K + a_k;
    const int ntiles = K / GEMM_BK;
    int fl = 0;
    for (int t = 0; t < ntiles; ++t) {
        const int k0 = t * GEMM_BK;
        const float4 av = *(const float4*)(Arow + k0);
        float4 bv;
        const int gn = bn + b_n;
        const float* Bp = B + (size_t)(k0 + b_k) * N + gn;
        if (gn + 3 < N) {
            bv = *(const float4*)Bp;
        } else {
            bv.x = (gn + 0 < N) ? Bp[0] : 0.f;
            bv.y = (gn + 1 < N) ? Bp[1] : 0.f;
            bv.z = (gn + 2 < N) ? Bp[2] : 0.f;
            bv.w = (gn + 3 < N) ? Bp[3] : 0.f;
        }
        __syncthreads();
        As[a_k + 0][a_r] = av.x;
        As[a_k + 1][a_r] = av.y;
        As[a_k + 2][a_r] = av.z;
        As[a_k + 3][a_r] = av.w;
        *(float4*)(&Bs[b_k][b_n]) = bv;
        __syncthreads();
        #pragma unroll
        for (int kk = 0; kk < GEMM_BK; ++kk) {
            const float4 a4 = *(const float4*)(&As[kk][ty << 2]);
            const float4 b4 = *(const float4*)(&Bs[kk][tx << 2]);
            const float ar[4] = {a4.x, a4.y, a4.z, a4.w};
            const float br[4] = {b4.x, b4.y, b4.z, b4.w};
            #pragma unroll
            for (int i = 0; i < 4; ++i) {
                #pragma unroll
                for (int j = 0; j < 4; ++j)
                    accc[i][j] = fmaf(ar[i], br[j], accc[i][j]);
            }
        }
        if (++fl == 4) {  // flush chunk (64 K-terms) into f64 totals
            fl = 0;
            #pragma unroll
            for (int i = 0; i < 4; ++i) {
                #pragma unroll
                for (int j = 0; j < 4; ++j) {
                    acct[i][j] += (double)accc[i][j];
                    accc[i][j] = 0.f;
                }
            }
        }
    }
    if (fl) {
        #pragma unroll
        for (int i = 0; i < 4; ++i) {
            #pragma unroll
            for (int j = 0; j < 4; ++j) acct[i][j] += (double)accc[i][j];
        }
    }
    #pragma unroll
    for (int i = 0; i < 4; ++i) {
        const int row = bm + (ty << 2) + i;
        #pragma unroll
        for (int j = 0; j < 4; ++j) {
            const int col = bn + (tx << 2) + j;
            if (col < N) {
                float v = (float)acct[i][j] + bias[col];
                if (ACT) v = tanhf(v);
                C[(size_t)row * N + col] = v;
            }
        }
    }
}

// cnorm[k] = sum_j codebook[k][j]^2, one wave per row.
__global__ __launch_bounds__(64) void cnorm_k(
    const float* __restrict__ CB, float* __restrict__ cn)
{
    const int k = blockIdx.x;
    const float* row = CB + (size_t)k * 512;
    float s = 0.f;
    #pragma unroll
    for (int u = 0; u < 8; ++u) {
        const float v = row[threadIdx.x + 64 * u];
        s = fmaf(v, v, s);
    }
    #pragma unroll
    for (int m = 32; m; m >>= 1) s += __shfl_down(s, m);
    if (threadIdx.x == 0) cn[k] = s;
}

__global__ void init_packed(unsigned long long* __restrict__ p)
{
    p[blockIdx.x * 256 + threadIdx.x] = ~0ull;
}

__device__ __forceinline__ unsigned int float_orderable(float f)
{
    unsigned int b = __float_as_uint(f);
    return (b & 0x80000000u) ? ~b : (b | 0x80000000u);
}

// scores s[i,k] = cnorm[k] - 2 * z_i . c_k  (||z||^2 offset dropped: argmin-
// invariant and removes large-offset rounding). Per-row running min merged via
// packed (orderable_score<<32 | k) atomicMin -> smallest score, then smallest
// index on exact ties, matching np.argmin.
__global__ __launch_bounds__(256) void vq_score_min(
    const float* __restrict__ Z, const float* __restrict__ CB,
    const float* __restrict__ cnorm, unsigned long long* __restrict__ packed)
{
    __shared__ float Zs[16][64];
    __shared__ float Cs[16][64];
    const int tid = threadIdx.x;
    const int tx = tid & 15;
    const int ty = tid >> 4;
    const int bi = blockIdx.y * 64;  // z rows
    const int bk = blockIdx.x * 64;  // codebook rows
    const int l_r = tid >> 2;
    const int l_j = (tid & 3) << 2;

    float acc[4][4] = {{0.f}};
    const float* Zp = Z  + (size_t)(bi + l_r) * 512 + l_j;
    const float* Cp = CB + (size_t)(bk + l_r) * 512 + l_j;
    for (int t = 0; t < 512 / 16; ++t) {
        const float4 zv = *(const float4*)(Zp + t * 16);
        const float4 cv = *(const float4*)(Cp + t * 16);
        __syncthreads();
        Zs[l_j + 0][l_r] = zv.x; Zs[l_j + 1][l_r] = zv.y;
        Zs[l_j + 2][l_r] = zv.z; Zs[l_j + 3][l_r] = zv.w;
        Cs[l_j + 0][l_r] = cv.x; Cs[l_j + 1][l_r] = cv.y;
        Cs[l_j + 2][l_r] = cv.z; Cs[l_j + 3][l_r] = cv.w;
        __syncthreads();
        #pragma unroll
        for (int jj = 0; jj < 16; ++jj) {
            const float4 z4 = *(const float4*)(&Zs[jj][ty << 2]);
            const float4 c4 = *(const float4*)(&Cs[jj][tx << 2]);
            const float zr[4] = {z4.x, z4.y, z4.z, z4.w};
            const float cr[4] = {c4.x, c4.y, c4.z, c4.w};
            #pragma unroll
            for (int i = 0; i < 4; ++i) {
                #pragma unroll
                for (int j = 0; j < 4; ++j)
                    acc[i][j] = fmaf(zr[i], cr[j], acc[i][j]);
            }
        }
    }
    #pragma unroll
    for (int i = 0; i < 4; ++i) {
        unsigned long long best = ~0ull;
        #pragma unroll
        for (int j = 0; j < 4; ++j) {
            const int k = bk + (tx << 2) + j;
            const float s = fmaf(-2.f, acc[i][j], cnorm[k]);
            const unsigned long long pv =
                ((unsigned long long)float_orderable(s) << 32) | (unsigned int)k;
            best = pv < best ? pv : best;
        }
        #pragma unroll
        for (int m = 1; m <= 8; m <<= 1) {
            const unsigned long long o = __shfl_xor(best, m);
            best = o < best ? o : best;
        }
        if (tx == 0) atomicMin(&packed[bi + (ty << 2) + i], best);
    }
}

// Gather quantized rows, write them to d_out (quantized_st == quantized in
// forward) and to an aligned ws buffer for the decoder; accumulate
// sum((q - z)^2) block partials in f64.
__global__ __launch_bounds__(256) void quant_loss(
    const unsigned long long* __restrict__ packed, const float* __restrict__ CB,
    const float* __restrict__ Z, float* __restrict__ qout,
    float* __restrict__ qbuf, double* __restrict__ partials)
{
    const int gid = blockIdx.x * 256 + threadIdx.x;
    const int i = gid >> 7;              // 128 threads per row of 512
    const int j = (gid & 127) << 2;
    const int k = (int)(packed[i] & 0xffffffffull);
    const float4 c = *(const float4*)(CB + (size_t)k * 512 + j);
    const float4 z = *(const float4*)(Z  + (size_t)i * 512 + j);

    const size_t o = (size_t)i * 512 + j;
    qout[o + 0] = c.x; qout[o + 1] = c.y; qout[o + 2] = c.z; qout[o + 3] = c.w;
    *(float4*)(qbuf + o) = c;

    const float d0 = c.x - z.x, d1 = c.y - z.y, d2 = c.z - z.z, d3 = c.w - z.w;
    float local = d0 * d0 + d1 * d1 + d2 * d2 + d3 * d3;
    #pragma unroll
    for (int m = 32; m; m >>= 1) local += __shfl_down(local, m);
    __shared__ float wsum[4];
    if ((threadIdx.x & 63) == 0) wsum[threadIdx.x >> 6] = local;
    __syncthreads();
    if (threadIdx.x == 0) {
        partials[blockIdx.x] = (double)wsum[0] + (double)wsum[1] +
                               (double)wsum[2] + (double)wsum[3];
    }
}

__global__ __launch_bounds__(256) void loss_final(
    const double* __restrict__ partials, float* __restrict__ out)
{
    double s = 0.0;
    for (int u = threadIdx.x; u < 2048; u += 256) s += partials[u];
    #pragma unroll
    for (int m = 32; m; m >>= 1) s += __shfl_down(s, m);
    __shared__ double ws[4];
    if ((threadIdx.x & 63) == 0) ws[threadIdx.x >> 6] = s;
    __syncthreads();
    if (threadIdx.x == 0) {
        const double total = ws[0] + ws[1] + ws[2] + ws[3];
        out[0] = (float)(1.25 * total / 2097152.0);  // (1 + 0.25) * mean
    }
}

extern "C" void kernel_launch(void* const* d_in, const int* in_sizes, int n_in,
                              void* d_out, int out_size, void* d_ws, size_t ws_size,
                              hipStream_t stream)
{
    const float* x  = (const float*)d_in[0];
    const float* W1 = (const float*)d_in[1];
    const float* b1 = (const float*)d_in[2];
    const float* W2 = (const float*)d_in[3];
    const float* b2 = (const float*)d_in[4];
    const float* W3 = (const float*)d_in[5];
    const float* b3 = (const float*)d_in[6];
    const float* CB = (const float*)d_in[7];
    const float* W4 = (const float*)d_in[8];
    const float* b4 = (const float*)d_in[9];
    const float* W5 = (const float*)d_in[10];
    const float* b5 = (const float*)d_in[11];
    const float* W6 = (const float*)d_in[12];
    const float* b6 = (const float*)d_in[13];

    float* out   = (float*)d_out;
    float* xrec  = out + 1;
    float* qout  = out + 1 + (size_t)4096 * 20000;

    char* ws = (char*)d_ws;
    float* bufA = (float*)(ws + 0);          // 4096x2048 f32 (z1, later h2)
    float* bufB = (float*)(ws + 33554432);   // 4096x1024 f32 (z2, later h1)
    float* bufC = (float*)(ws + 50331648);   // 4096x512  f32 (z3)
    float* cn   = (float*)(ws + 58720256);   // 8192 f32
    unsigned long long* packed = (unsigned long long*)(ws + 58753024);  // 4096 u64
    double* partials = (double*)(ws + 58785792);                        // 2048 f64
    float* bufQ = bufA;  // z1 dead after layer 2; reuse first 8.4 MB for q

    const dim3 blk(256);

    // encoder
    gemm_f32<1><<<dim3(2048 / 64, 4096 / 64), blk, 0, stream>>>(x,    W1, b1, bufA, 4096, 2048,  20000);
    gemm_f32<1><<<dim3(1024 / 64, 4096 / 64), blk, 0, stream>>>(bufA, W2, b2, bufB, 4096, 1024,  2048);
    gemm_f32<1><<<dim3(512  / 64, 4096 / 64), blk, 0, stream>>>(bufB, W3, b3, bufC, 4096, 512,   1024);

    // vector quantization
    cnorm_k    <<<dim3(8192), dim3(64), 0, stream>>>(CB, cn);
    init_packed<<<dim3(16),   blk,      0, stream>>>(packed);
    vq_score_min<<<dim3(8192 / 64, 4096 / 64), blk, 0, stream>>>(bufC, CB, cn, packed);
    quant_loss <<<dim3(2048), blk, 0, stream>>>(packed, CB, bufC, qout, bufQ, partials);
    loss_final <<<dim3(1),    blk, 0, stream>>>(partials, out);

    // decoder
    gemm_f32<1><<<dim3(1024 / 64, 4096 / 64), blk, 0, stream>>>(bufQ, W4, b4, bufB, 4096, 1024,  512);
    gemm_f32<1><<<dim3(2048 / 64, 4096 / 64), blk, 0, stream>>>(bufB, W5, b5, bufA, 4096, 2048,  1024);
    gemm_f32<0><<<dim3((20000 + 63) / 64, 4096 / 64), blk, 0, stream>>>(bufA, W6, b6, xrec, 4096, 20000, 2048);
}

// Round 2
// 1729.573 us; speedup vs baseline: 6.7540x; 6.7540x over previous
//
#include <hip/hip_runtime.h>
#include <hip/hip_bf16.h>
#include <math.h>

// ---------------------------------------------------------------------------
// VQ-VAE forward on MFMA. B=4096, G=20000, dims 2048/1024/512, K=8192 codes.
// All GEMMs: bf16 inputs, f32 MFMA accum (m97-style 128x128 tile, BK=32,
// 4 waves, global_load_lds width-16 staging, 16x16x32 bf16 MFMA).
// Outputs: [loss(1)] [x_recon 4096x20000 f32] [quantized_st 4096x512 f32].
// Threshold is a global absolute 4.98e-4 => argmin flips (<=2.44e-4) are safe.
// ---------------------------------------------------------------------------

typedef short v8s __attribute__((ext_vector_type(8)));
typedef float v4f __attribute__((ext_vector_type(4)));
typedef unsigned short u16;
typedef unsigned long long u64;

typedef const unsigned int __attribute__((address_space(1)))* as1p;
typedef unsigned int __attribute__((address_space(3)))* as3p;

__device__ __forceinline__ void gload_lds16(const void* g, void* l) {
    __builtin_amdgcn_global_load_lds((as1p)g, (as3p)l, 16, 0, 0);
}

__device__ __forceinline__ u16 f2b(float f) {
    return __builtin_bit_cast(u16, __float2bfloat16(f));
}

// ---------------------------------------------------------------------------
// GEMM: C[M,N] = epi(A[M,K] @ Bt[N,K]^T + bias)
// EPI: 0 = bias, 1 = tanh(x+bias), 2 = bias - 2*x (VQ scores, bias = cnorm)
// WB: write bf16 C, WF: write f32 C. grid = (ceil(N/128), M/128), block 256.
// Bt must have ceil(N/128)*128 valid (readable) rows; cols >= N are masked.
// ---------------------------------------------------------------------------
template<int EPI, int WB, int WF>
__global__ __launch_bounds__(256, 2) void mfma_gemm(
    const u16* __restrict__ A, const u16* __restrict__ Bt,
    const float* __restrict__ bias, float* __restrict__ Cf,
    u16* __restrict__ Cb, int M, int N, int K)
{
    __shared__ u16 As[128 * 32];
    __shared__ u16 Bs[128 * 32];
    const int tid = threadIdx.x;
    const int wv = tid >> 6;
    const int ln = tid & 63;
    const int bm = blockIdx.y * 128;
    const int bn = blockIdx.x * 128;

    // staging: wave wv covers LDS bytes [wv*2048, wv*2048+2048) of each tile,
    // two 1KB wave-insts; lane ln -> row = wv*32 + j*16 + (ln>>2), k = (ln&3)*8
    const int srow = wv * 32 + (ln >> 2);
    const int skel = (ln & 3) * 8;
    const u16* Ap0 = A + (size_t)(bm + srow) * K + skel;
    const u16* Ap1 = Ap0 + (size_t)16 * K;
    const u16* Bp0 = Bt + (size_t)(bn + srow) * K + skel;
    const u16* Bp1 = Bp0 + (size_t)16 * K;
    u16* lA0 = As + wv * 1024;
    u16* lA1 = lA0 + 512;
    u16* lB0 = Bs + wv * 1024;
    u16* lB1 = lB0 + 512;

    const int wr = wv >> 1, wc = wv & 1;
    const int fr = ln & 15;          // M (A) / N (B) index within fragment
    const int kg = (ln >> 4) * 8;    // k group
    const u16* Afp = As + (wr * 64 + fr) * 32 + kg;
    const u16* Bfp = Bs + (wc * 64 + fr) * 32 + kg;

    v4f acc[4][4];
    #pragma unroll
    for (int m = 0; m < 4; ++m)
        #pragma unroll
        for (int n = 0; n < 4; ++n) acc[m][n] = (v4f)(0.f);

    for (int k0 = 0; k0 < K; k0 += 32) {
        __syncthreads();   // previous compute done before LDS overwrite
        gload_lds16(Ap0 + k0, lA0);
        gload_lds16(Ap1 + k0, lA1);
        gload_lds16(Bp0 + k0, lB0);
        gload_lds16(Bp1 + k0, lB1);
        __syncthreads();   // drains vmcnt, staged tile visible
        v8s a[4], b[4];
        #pragma unroll
        for (int m = 0; m < 4; ++m) a[m] = *(const v8s*)(Afp + m * 512);
        #pragma unroll
        for (int n = 0; n < 4; ++n) b[n] = *(const v8s*)(Bfp + n * 512);
        #pragma unroll
        for (int m = 0; m < 4; ++m)
            #pragma unroll
            for (int n = 0; n < 4; ++n)
                acc[m][n] = __builtin_amdgcn_mfma_f32_16x16x32_bf16(
                    a[m], b[n], acc[m][n], 0, 0, 0);
    }

    // C/D layout: col = lane&15, row = (lane>>4)*4 + reg   [m89-verified]
    const int rb = (ln >> 4) * 4;
    #pragma unroll
    for (int m = 0; m < 4; ++m) {
        const int row = bm + wr * 64 + m * 16 + rb;
        #pragma unroll
        for (int n = 0; n < 4; ++n) {
            const int col = bn + wc * 64 + n * 16 + fr;
            if (col < N) {
                const float bv = bias[col];
                #pragma unroll
                for (int r = 0; r < 4; ++r) {
                    float v = acc[m][n][r];
                    if (EPI == 2) v = bv - 2.f * v;
                    else { v += bv; if (EPI == 1) v = tanhf(v); }
                    if (WF) Cf[(size_t)(row + r) * N + col] = v;
                    if (WB) Cb[(size_t)(row + r) * N + col] = f2b(v);
                }
            }
        }
    }
}

// f32 -> bf16 elementwise, 8/thread, grid-stride. n8 = n/8.
__global__ __launch_bounds__(256) void conv_bf16(
    const float* __restrict__ in, u16* __restrict__ out, long n8)
{
    const long stride = (long)gridDim.x * 256;
    for (long i = (long)blockIdx.x * 256 + threadIdx.x; i < n8; i += stride) {
        const float4 a = ((const float4*)in)[i * 2];
        const float4 b = ((const float4*)in)[i * 2 + 1];
        v8s o;
        o[0] = (short)f2b(a.x); o[1] = (short)f2b(a.y);
        o[2] = (short)f2b(a.z); o[3] = (short)f2b(a.w);
        o[4] = (short)f2b(b.x); o[5] = (short)f2b(b.y);
        o[6] = (short)f2b(b.z); o[7] = (short)f2b(b.w);
        *(v8s*)(out + i * 8) = o;
    }
}

// W[K][N] f32 -> Wt[N][K] bf16 (rows n>=N of padded Wt left untouched; they
// only feed masked-out output columns). K % 32 == 0. block (32,8).
__global__ __launch_bounds__(256) void trans_bf16(
    const float* __restrict__ W, u16* __restrict__ Wt, int K, int N)
{
    __shared__ float t[32][33];
    const int tx = threadIdx.x, ty = threadIdx.y;
    const int n0 = blockIdx.x * 32, k0 = blockIdx.y * 32;
    #pragma unroll
    for (int i = 0; i < 32; i += 8) {
        const int n = n0 + tx;
        t[ty + i][tx] = (n < N) ? W[(size_t)(k0 + ty + i) * N + n] : 0.f;
    }
    __syncthreads();
    #pragma unroll
    for (int i = 0; i < 32; i += 8) {
        const int n = n0 + ty + i;
        if (n < N) Wt[(size_t)n * K + k0 + tx] = f2b(t[tx][ty + i]);
    }
}

// cnorm[k] = ||codebook[k]||^2 (f32 codebook), one wave per row.
__global__ __launch_bounds__(64) void cnorm_k(
    const float* __restrict__ CB, float* __restrict__ cn)
{
    const float* row = CB + (size_t)blockIdx.x * 512;
    float s = 0.f;
    #pragma unroll
    for (int u = 0; u < 8; ++u) {
        const float v = row[threadIdx.x + 64 * u];
        s = fmaf(v, v, s);
    }
    #pragma unroll
    for (int m = 32; m; m >>= 1) s += __shfl_down(s, m);
    if (threadIdx.x == 0) cn[blockIdx.x] = s;
}

__device__ __forceinline__ unsigned int float_orderable(float f)
{
    unsigned int b = __float_as_uint(f);
    return (b & 0x80000000u) ? ~b : (b | 0x80000000u);
}

// per-row argmin over scores [4096][8192]; one block per row, no atomics.
__global__ __launch_bounds__(256) void row_argmin(
    const float* __restrict__ S, u64* __restrict__ packed)
{
    const float4* p = (const float4*)(S + (size_t)blockIdx.x * 8192);
    u64 best = ~0ull;
    for (int j = threadIdx.x; j < 2048; j += 256) {
        const float4 v = p[j];
        const int k = j << 2;
        const float vs[4] = {v.x, v.y, v.z, v.w};
        #pragma unroll
        for (int e = 0; e < 4; ++e) {
            const u64 pv = ((u64)float_orderable(vs[e]) << 32) | (unsigned)(k + e);
            best = pv < best ? pv : best;
        }
    }
    #pragma unroll
    for (int m = 1; m < 64; m <<= 1) {
        const u64 o = __shfl_xor(best, m);
        best = o < best ? o : best;
    }
    __shared__ u64 wb[4];
    if ((threadIdx.x & 63) == 0) wb[threadIdx.x >> 6] = best;
    __syncthreads();
    if (threadIdx.x == 0) {
        best = wb[0];
        for (int w = 1; w < 4; ++w) best = wb[w] < best ? wb[w] : best;
        packed[blockIdx.x] = best;
    }
}

// gather q rows -> qout (f32, d_out) + qb (bf16, decoder input);
// block partials of sum((q-z)^2) in f64.
__global__ __launch_bounds__(256) void quant_loss(
    const u64* __restrict__ packed, const float* __restrict__ CB,
    const float* __restrict__ Z, float* __restrict__ qout,
    u16* __restrict__ qb, double* __restrict__ partials)
{
    const int gid = blockIdx.x * 256 + threadIdx.x;
    const int i = gid >> 7;
    const int j = (gid & 127) << 2;
    const int k = (int)(packed[i] & 0xffffffffull);
    const float4 c = *(const float4*)(CB + (size_t)k * 512 + j);
    const float4 z = *(const float4*)(Z + (size_t)i * 512 + j);
    const size_t o = (size_t)i * 512 + j;
    qout[o + 0] = c.x; qout[o + 1] = c.y; qout[o + 2] = c.z; qout[o + 3] = c.w;
    qb[o + 0] = f2b(c.x); qb[o + 1] = f2b(c.y);
    qb[o + 2] = f2b(c.z); qb[o + 3] = f2b(c.w);
    const float d0 = c.x - z.x, d1 = c.y - z.y, d2 = c.z - z.z, d3 = c.w - z.w;
    float local = d0 * d0 + d1 * d1 + d2 * d2 + d3 * d3;
    #pragma unroll
    for (int m = 32; m; m >>= 1) local += __shfl_down(local, m);
    __shared__ float wsum[4];
    if ((threadIdx.x & 63) == 0) wsum[threadIdx.x >> 6] = local;
    __syncthreads();
    if (threadIdx.x == 0)
        partials[blockIdx.x] = (double)wsum[0] + (double)wsum[1] +
                               (double)wsum[2] + (double)wsum[3];
}

__global__ __launch_bounds__(256) void loss_final(
    const double* __restrict__ partials, float* __restrict__ out)
{
    double s = 0.0;
    for (int u = threadIdx.x; u < 2048; u += 256) s += partials[u];
    #pragma unroll
    for (int m = 32; m; m >>= 1) s += __shfl_down(s, m);
    __shared__ double ws[4];
    if ((threadIdx.x & 63) == 0) ws[threadIdx.x >> 6] = s;
    __syncthreads();
    if (threadIdx.x == 0)
        out[0] = (float)(1.25 * (ws[0] + ws[1] + ws[2] + ws[3]) / 2097152.0);
}

extern "C" void kernel_launch(void* const* d_in, const int* in_sizes, int n_in,
                              void* d_out, int out_size, void* d_ws, size_t ws_size,
                              hipStream_t stream)
{
    const float* x  = (const float*)d_in[0];
    const float* W1 = (const float*)d_in[1];
    const float* b1 = (const float*)d_in[2];
    const float* W2 = (const float*)d_in[3];
    const float* b2 = (const float*)d_in[4];
    const float* W3 = (const float*)d_in[5];
    const float* b3 = (const float*)d_in[6];
    const float* CB = (const float*)d_in[7];
    const float* W4 = (const float*)d_in[8];
    const float* b4 = (const float*)d_in[9];
    const float* W5 = (const float*)d_in[10];
    const float* b5 = (const float*)d_in[11];
    const float* W6 = (const float*)d_in[12];
    const float* b6 = (const float*)d_in[13];

    float* out  = (float*)d_out;
    float* xrec = out + 1;
    float* qout = out + 1 + (size_t)4096 * 20000;

    // scratch inside d_out's x_recon region (dead until final GEMM):
    u16*   xb     = (u16*)((char*)d_out + 16);                    // 160.0 MB
    float* scores = (float*)((char*)d_out + 16 + 163840000);      // 134.2 MB

    char* ws = (char*)d_ws;
    u16* WT16 = (u16*)(ws + 0);          // [2048][20000] Wt1, later [20096][2048] Wt6
    u16* WT2  = (u16*)(ws + 82313216);   // [1024][2048]
    u16* WT3  = (u16*)(ws + 86507520);   // [512][1024]
    u16* CBB  = (u16*)(ws + 87556096);   // [8192][512]
    u16* WT4  = (u16*)(ws + 95944704);   // [1024][512]
    u16* WT5  = (u16*)(ws + 96993280);   // [2048][1024]
    u16* ACT1 = (u16*)(ws + 101187584);  // [4096][2048] z1, later h2
    u16* ACT2 = (u16*)(ws + 117964800);  // [4096][1024] z2, later h1
    float* Z3F = (float*)(ws + 126353408); // [4096][512]
    u16* Z3B  = (u16*)(ws + 134742016);  // [4096][512]
    u16* QB   = (u16*)(ws + 138936320);  // [4096][512]
    float* CN = (float*)(ws + 143130624);
    u64* PACKED = (u64*)(ws + 143163392);
    double* PART = (double*)(ws + 143196160);

    const dim3 blk(256);

    // ---- precompute: bf16 conversions + weight transposes ----
    conv_bf16<<<dim3(2048), blk, 0, stream>>>(x, xb, 10240000L);
    conv_bf16<<<dim3(2048), blk, 0, stream>>>(CB, CBB, 524288L);
    trans_bf16<<<dim3(64, 625), dim3(32, 8), 0, stream>>>(W1, WT16, 20000, 2048);
    trans_bf16<<<dim3(32, 64),  dim3(32, 8), 0, stream>>>(W2, WT2, 2048, 1024);
    trans_bf16<<<dim3(16, 32),  dim3(32, 8), 0, stream>>>(W3, WT3, 1024, 512);
    trans_bf16<<<dim3(32, 16),  dim3(32, 8), 0, stream>>>(W4, WT4, 512, 1024);
    trans_bf16<<<dim3(64, 32),  dim3(32, 8), 0, stream>>>(W5, WT5, 1024, 2048);
    cnorm_k<<<dim3(8192), dim3(64), 0, stream>>>(CB, CN);

    // ---- encoder ----
    mfma_gemm<1, 1, 0><<<dim3(16, 32), blk, 0, stream>>>(
        xb, WT16, b1, nullptr, ACT1, 4096, 2048, 20000);
    // Wt1 dead; transpose W6 into the same arena (stream-ordered)
    trans_bf16<<<dim3(625, 64), dim3(32, 8), 0, stream>>>(W6, WT16, 2048, 20000);
    mfma_gemm<1, 1, 0><<<dim3(8, 32), blk, 0, stream>>>(
        ACT1, WT2, b2, nullptr, ACT2, 4096, 1024, 2048);
    mfma_gemm<1, 1, 1><<<dim3(4, 32), blk, 0, stream>>>(
        ACT2, WT3, b3, Z3F, Z3B, 4096, 512, 1024);

    // ---- VQ: scores = cnorm - 2 z.c, argmin, gather, loss ----
    mfma_gemm<2, 0, 1><<<dim3(64, 32), blk, 0, stream>>>(
        Z3B, CBB, CN, scores, nullptr, 4096, 8192, 512);
    row_argmin<<<dim3(4096), blk, 0, stream>>>(scores, PACKED);
    quant_loss<<<dim3(2048), blk, 0, stream>>>(PACKED, CB, Z3F, qout, QB, PART);
    loss_final<<<dim3(1), blk, 0, stream>>>(PART, out);

    // ---- decoder ----
    mfma_gemm<1, 1, 0><<<dim3(8, 32), blk, 0, stream>>>(
        QB, WT4, b4, nullptr, ACT2, 4096, 1024, 512);
    mfma_gemm<1, 1, 0><<<dim3(16, 32), blk, 0, stream>>>(
        ACT2, WT5, b5, nullptr, ACT1, 4096, 2048, 1024);
    mfma_gemm<0, 0, 1><<<dim3(157, 32), blk, 0, stream>>>(
        ACT1, WT16, b6, xrec, nullptr, 4096, 20000, 2048);
}

// Round 3
// 1622.236 us; speedup vs baseline: 7.2009x; 1.0662x over previous
//
#include <hip/hip_runtime.h>
#include <hip/hip_bf16.h>
#include <math.h>

// ---------------------------------------------------------------------------
// VQ-VAE forward on MFMA. B=4096, G=20000, dims 2048/1024/512, K=8192 codes.
// bf16-input / f32-accum MFMA GEMMs (m97 structure). Round 3: split-K GEMM1
// (grid was 512 blocks = 2/CU, occupancy-limited) + argmin fused into the
// VQ-score GEMM epilogue (kills 268 MB of score write+read traffic).
// ---------------------------------------------------------------------------

typedef short v8s __attribute__((ext_vector_type(8)));
typedef float v4f __attribute__((ext_vector_type(4)));
typedef unsigned short u16;
typedef unsigned long long u64;

typedef const unsigned int __attribute__((address_space(1)))* as1p;
typedef unsigned int __attribute__((address_space(3)))* as3p;

__device__ __forceinline__ void gload_lds16(const void* g, void* l) {
    __builtin_amdgcn_global_load_lds((as1p)g, (as3p)l, 16, 0, 0);
}

__device__ __forceinline__ u16 f2b(float f) {
    return __builtin_bit_cast(u16, __float2bfloat16(f));
}

__device__ __forceinline__ unsigned int float_orderable(float f)
{
    unsigned int b = __float_as_uint(f);
    return (b & 0x80000000u) ? ~b : (b | 0x80000000u);
}

// ---------------------------------------------------------------------------
// GEMM: C[M,N] = epi(A[M,K] @ Bt[N,K]^T [+ bias])
// EPI: 0 = +bias, 1 = tanh(+bias), 2 = VQ argmin epilogue (score = bias-2*acc,
//      packed u64 atomicMin per row, no C write), 3 = raw f32 partial,
//      K-chunked via blockIdx.z (chunks of 156*32=4992, last takes remainder).
// WB: write bf16 C, WF: write f32 C. grid=(ceil(N/128), M/128[, chunks]).
// ---------------------------------------------------------------------------
template<int EPI, int WB, int WF>
__global__ __launch_bounds__(256, 2) void mfma_gemm(
    const u16* __restrict__ A, const u16* __restrict__ Bt,
    const float* __restrict__ bias, float* __restrict__ Cf,
    u16* __restrict__ Cb, u64* __restrict__ packed, int M, int N, int K)
{
    __shared__ u16 As[128 * 32];
    __shared__ u16 Bs[128 * 32];
    const int tid = threadIdx.x;
    const int wv = tid >> 6;
    const int ln = tid & 63;
    const int bm = blockIdx.y * 128;
    const int bn = blockIdx.x * 128;

    int kBeg = 0, kEnd = K;
    if (EPI == 3) {
        kBeg = blockIdx.z * 4992;
        kEnd = (blockIdx.z == gridDim.z - 1) ? K : kBeg + 4992;
        Cf += (size_t)blockIdx.z * ((size_t)M * N);
    }

    // staging: wave wv covers LDS bytes [wv*2048, +2048) of each tile
    const int srow = wv * 32 + (ln >> 2);
    const int skel = (ln & 3) * 8;
    const u16* Ap0 = A + (size_t)(bm + srow) * K + skel;
    const u16* Ap1 = Ap0 + (size_t)16 * K;
    const u16* Bp0 = Bt + (size_t)(bn + srow) * K + skel;
    const u16* Bp1 = Bp0 + (size_t)16 * K;
    u16* lA0 = As + wv * 1024;
    u16* lA1 = lA0 + 512;
    u16* lB0 = Bs + wv * 1024;
    u16* lB1 = lB0 + 512;

    const int wr = wv >> 1, wc = wv & 1;
    const int fr = ln & 15;          // M (A) / N (B) index within fragment
    const int kg = (ln >> 4) * 8;    // k group
    const u16* Afp = As + (wr * 64 + fr) * 32 + kg;
    const u16* Bfp = Bs + (wc * 64 + fr) * 32 + kg;

    v4f acc[4][4];
    #pragma unroll
    for (int m = 0; m < 4; ++m)
        #pragma unroll
        for (int n = 0; n < 4; ++n) acc[m][n] = (v4f)(0.f);

    for (int k0 = kBeg; k0 < kEnd; k0 += 32) {
        __syncthreads();   // previous compute done before LDS overwrite
        gload_lds16(Ap0 + k0, lA0);
        gload_lds16(Ap1 + k0, lA1);
        gload_lds16(Bp0 + k0, lB0);
        gload_lds16(Bp1 + k0, lB1);
        __syncthreads();   // drains vmcnt, staged tile visible
        v8s a[4], b[4];
        #pragma unroll
        for (int m = 0; m < 4; ++m) a[m] = *(const v8s*)(Afp + m * 512);
        #pragma unroll
        for (int n = 0; n < 4; ++n) b[n] = *(const v8s*)(Bfp + n * 512);
        #pragma unroll
        for (int m = 0; m < 4; ++m)
            #pragma unroll
            for (int n = 0; n < 4; ++n)
                acc[m][n] = __builtin_amdgcn_mfma_f32_16x16x32_bf16(
                    a[m], b[n], acc[m][n], 0, 0, 0);
    }

    // C/D layout: col = lane&15, row = (lane>>4)*4 + reg   [m89-verified]
    const int rb = (ln >> 4) * 4;

    if constexpr (EPI == 2) {
        // fused per-row argmin over this block's 128-col strip
        __shared__ u64 smin[128];
        if (tid < 128) smin[tid] = ~0ull;
        __syncthreads();
        #pragma unroll
        for (int m = 0; m < 4; ++m) {
            #pragma unroll
            for (int r = 0; r < 4; ++r) {
                u64 best = ~0ull;
                #pragma unroll
                for (int n = 0; n < 4; ++n) {
                    const int col = bn + wc * 64 + n * 16 + fr;
                    const float s = fmaf(-2.f, acc[m][n][r], bias[col]);
                    const u64 pv =
                        ((u64)float_orderable(s) << 32) | (unsigned)col;
                    best = pv < best ? pv : best;
                }
                #pragma unroll
                for (int msk = 1; msk <= 8; msk <<= 1) {
                    const u64 o = __shfl_xor(best, msk);
                    best = o < best ? o : best;
                }
                if (fr == 0) atomicMin(&smin[wr * 64 + m * 16 + rb + r], best);
            }
        }
        __syncthreads();
        if (tid < 128) atomicMin(&packed[bm + tid], smin[tid]);
    } else {
        #pragma unroll
        for (int m = 0; m < 4; ++m) {
            const int row = bm + wr * 64 + m * 16 + rb;
            #pragma unroll
            for (int n = 0; n < 4; ++n) {
                const int col = bn + wc * 64 + n * 16 + fr;
                if (col < N) {
                    const float bv = (EPI == 3) ? 0.f : bias[col];
                    #pragma unroll
                    for (int r = 0; r < 4; ++r) {
                        float v = acc[m][n][r];
                        if (EPI != 3) { v += bv; if (EPI == 1) v = tanhf(v); }
                        if (WF) Cf[(size_t)(row + r) * N + col] = v;
                        if (WB) Cb[(size_t)(row + r) * N + col] = f2b(v);
                    }
                }
            }
        }
    }
}

// out[i] = bf16(tanh(P0+P1+P2+P3+bias)), 8 elems/thread. cs = chunk stride.
__global__ __launch_bounds__(256) void reduce_tanh4(
    const float* __restrict__ P, const float* __restrict__ bias,
    u16* __restrict__ out, long n8, int N, size_t cs)
{
    const long stride = (long)gridDim.x * 256;
    for (long i = (long)blockIdx.x * 256 + threadIdx.x; i < n8; i += stride) {
        const size_t e0 = (size_t)i * 8;
        const int col = (int)(e0 & (size_t)(N - 1));
        float4 s0 = *(const float4*)(P + e0);
        float4 s1 = *(const float4*)(P + e0 + 4);
        #pragma unroll
        for (int c = 1; c < 4; ++c) {
            const float4 a = *(const float4*)(P + c * cs + e0);
            const float4 b = *(const float4*)(P + c * cs + e0 + 4);
            s0.x += a.x; s0.y += a.y; s0.z += a.z; s0.w += a.w;
            s1.x += b.x; s1.y += b.y; s1.z += b.z; s1.w += b.w;
        }
        const float4 bv0 = *(const float4*)(bias + col);
        const float4 bv1 = *(const float4*)(bias + col + 4);
        v8s o;
        o[0] = (short)f2b(tanhf(s0.x + bv0.x));
        o[1] = (short)f2b(tanhf(s0.y + bv0.y));
        o[2] = (short)f2b(tanhf(s0.z + bv0.z));
        o[3] = (short)f2b(tanhf(s0.w + bv0.w));
        o[4] = (short)f2b(tanhf(s1.x + bv1.x));
        o[5] = (short)f2b(tanhf(s1.y + bv1.y));
        o[6] = (short)f2b(tanhf(s1.z + bv1.z));
        o[7] = (short)f2b(tanhf(s1.w + bv1.w));
        *(v8s*)(out + e0) = o;
    }
}

// f32 -> bf16 elementwise, 8/thread, grid-stride. n8 = n/8.
__global__ __launch_bounds__(256) void conv_bf16(
    const float* __restrict__ in, u16* __restrict__ out, long n8)
{
    const long stride = (long)gridDim.x * 256;
    for (long i = (long)blockIdx.x * 256 + threadIdx.x; i < n8; i += stride) {
        const float4 a = ((const float4*)in)[i * 2];
        const float4 b = ((const float4*)in)[i * 2 + 1];
        v8s o;
        o[0] = (short)f2b(a.x); o[1] = (short)f2b(a.y);
        o[2] = (short)f2b(a.z); o[3] = (short)f2b(a.w);
        o[4] = (short)f2b(b.x); o[5] = (short)f2b(b.y);
        o[6] = (short)f2b(b.z); o[7] = (short)f2b(b.w);
        *(v8s*)(out + i * 8) = o;
    }
}

// W[K][N] f32 -> Wt[N][K] bf16. K % 32 == 0. block (32,8).
__global__ __launch_bounds__(256) void trans_bf16(
    const float* __restrict__ W, u16* __restrict__ Wt, int K, int N)
{
    __shared__ float t[32][33];
    const int tx = threadIdx.x, ty = threadIdx.y;
    const int n0 = blockIdx.x * 32, k0 = blockIdx.y * 32;
    #pragma unroll
    for (int i = 0; i < 32; i += 8) {
        const int n = n0 + tx;
        t[ty + i][tx] = (n < N) ? W[(size_t)(k0 + ty + i) * N + n] : 0.f;
    }
    __syncthreads();
    #pragma unroll
    for (int i = 0; i < 32; i += 8) {
        const int n = n0 + ty + i;
        if (n < N) Wt[(size_t)n * K + k0 + tx] = f2b(t[tx][ty + i]);
    }
}

// cnorm[k] = ||codebook[k]||^2 (f32), one wave per row.
__global__ __launch_bounds__(64) void cnorm_k(
    const float* __restrict__ CB, float* __restrict__ cn)
{
    const float* row = CB + (size_t)blockIdx.x * 512;
    float s = 0.f;
    #pragma unroll
    for (int u = 0; u < 8; ++u) {
        const float v = row[threadIdx.x + 64 * u];
        s = fmaf(v, v, s);
    }
    #pragma unroll
    for (int m = 32; m; m >>= 1) s += __shfl_down(s, m);
    if (threadIdx.x == 0) cn[blockIdx.x] = s;
}

__global__ void init_packed(u64* __restrict__ p)
{
    p[blockIdx.x * 256 + threadIdx.x] = ~0ull;
}

// gather q rows -> qout (f32, d_out) + qb (bf16, decoder input);
// block partials of sum((q-z)^2) in f64.
__global__ __launch_bounds__(256) void quant_loss(
    const u64* __restrict__ packed, const float* __restrict__ CB,
    const float* __restrict__ Z, float* __restrict__ qout,
    u16* __restrict__ qb, double* __restrict__ partials)
{
    const int gid = blockIdx.x * 256 + threadIdx.x;
    const int i = gid >> 7;
    const int j = (gid & 127) << 2;
    const int k = (int)(packed[i] & 0xffffffffull);
    const float4 c = *(const float4*)(CB + (size_t)k * 512 + j);
    const float4 z = *(const float4*)(Z + (size_t)i * 512 + j);
    const size_t o = (size_t)i * 512 + j;
    qout[o + 0] = c.x; qout[o + 1] = c.y; qout[o + 2] = c.z; qout[o + 3] = c.w;
    qb[o + 0] = f2b(c.x); qb[o + 1] = f2b(c.y);
    qb[o + 2] = f2b(c.z); qb[o + 3] = f2b(c.w);
    const float d0 = c.x - z.x, d1 = c.y - z.y, d2 = c.z - z.z, d3 = c.w - z.w;
    float local = d0 * d0 + d1 * d1 + d2 * d2 + d3 * d3;
    #pragma unroll
    for (int m = 32; m; m >>= 1) local += __shfl_down(local, m);
    __shared__ float wsum[4];
    if ((threadIdx.x & 63) == 0) wsum[threadIdx.x >> 6] = local;
    __syncthreads();
    if (threadIdx.x == 0)
        partials[blockIdx.x] = (double)wsum[0] + (double)wsum[1] +
                               (double)wsum[2] + (double)wsum[3];
}

__global__ __launch_bounds__(256) void loss_final(
    const double* __restrict__ partials, float* __restrict__ out)
{
    double s = 0.0;
    for (int u = threadIdx.x; u < 2048; u += 256) s += partials[u];
    #pragma unroll
    for (int m = 32; m; m >>= 1) s += __shfl_down(s, m);
    __shared__ double ws[4];
    if ((threadIdx.x & 63) == 0) ws[threadIdx.x >> 6] = s;
    __syncthreads();
    if (threadIdx.x == 0)
        out[0] = (float)(1.25 * (ws[0] + ws[1] + ws[2] + ws[3]) / 2097152.0);
}

extern "C" void kernel_launch(void* const* d_in, const int* in_sizes, int n_in,
                              void* d_out, int out_size, void* d_ws, size_t ws_size,
                              hipStream_t stream)
{
    const float* x  = (const float*)d_in[0];
    const float* W1 = (const float*)d_in[1];
    const float* b1 = (const float*)d_in[2];
    const float* W2 = (const float*)d_in[3];
    const float* b2 = (const float*)d_in[4];
    const float* W3 = (const float*)d_in[5];
    const float* b3 = (const float*)d_in[6];
    const float* CB = (const float*)d_in[7];
    const float* W4 = (const float*)d_in[8];
    const float* b4 = (const float*)d_in[9];
    const float* W5 = (const float*)d_in[10];
    const float* b5 = (const float*)d_in[11];
    const float* W6 = (const float*)d_in[12];
    const float* b6 = (const float*)d_in[13];

    float* out  = (float*)d_out;
    float* xrec = out + 1;
    float* qout = out + 1 + (size_t)4096 * 20000;

    // scratch inside d_out's x_recon region (dead until final GEMM):
    u16*   xb   = (u16*)((char*)d_out + 16);                     // 163.84 MB
    float* PART1 = (float*)((char*)d_out + 16 + 163840000);      // 134.2 MB

    char* ws = (char*)d_ws;
    u16* WT16 = (u16*)(ws + 0);          // [2048][20000] Wt1, later [20096][2048] Wt6
    u16* WT2  = (u16*)(ws + 82313216);   // [1024][2048]
    u16* WT3  = (u16*)(ws + 86507520);   // [512][1024]
    u16* CBB  = (u16*)(ws + 87556096);   // [8192][512]
    u16* WT4  = (u16*)(ws + 95944704);   // [1024][512]
    u16* WT5  = (u16*)(ws + 96993280);   // [2048][1024]
    u16* ACT1 = (u16*)(ws + 101187584);  // [4096][2048] z1, later h2
    u16* ACT2 = (u16*)(ws + 117964800);  // [4096][1024] z2, later h1
    float* Z3F = (float*)(ws + 126353408); // [4096][512]
    u16* Z3B  = (u16*)(ws + 134742016);  // [4096][512]
    u16* QB   = (u16*)(ws + 138936320);  // [4096][512]
    float* CN = (float*)(ws + 143130624);
    u64* PACKED = (u64*)(ws + 143163392);
    double* PART = (double*)(ws + 143196160);

    const dim3 blk(256);

    // ---- precompute: bf16 conversions + weight transposes ----
    conv_bf16<<<dim3(2048), blk, 0, stream>>>(x, xb, 10240000L);
    conv_bf16<<<dim3(2048), blk, 0, stream>>>(CB, CBB, 524288L);
    trans_bf16<<<dim3(64, 625), dim3(32, 8), 0, stream>>>(W1, WT16, 20000, 2048);
    trans_bf16<<<dim3(32, 64),  dim3(32, 8), 0, stream>>>(W2, WT2, 2048, 1024);
    trans_bf16<<<dim3(16, 32),  dim3(32, 8), 0, stream>>>(W3, WT3, 1024, 512);
    trans_bf16<<<dim3(32, 16),  dim3(32, 8), 0, stream>>>(W4, WT4, 512, 1024);
    trans_bf16<<<dim3(64, 32),  dim3(32, 8), 0, stream>>>(W5, WT5, 1024, 2048);
    cnorm_k<<<dim3(8192), dim3(64), 0, stream>>>(CB, CN);
    init_packed<<<dim3(16), blk, 0, stream>>>(PACKED);

    // ---- encoder ----
    // GEMM1 split-K: 4 chunks -> 2048 blocks (8/CU) instead of 512 (2/CU)
    mfma_gemm<3, 0, 1><<<dim3(16, 32, 4), blk, 0, stream>>>(
        xb, WT16, nullptr, PART1, nullptr, nullptr, 4096, 2048, 20000);
    reduce_tanh4<<<dim3(4096), blk, 0, stream>>>(
        PART1, b1, ACT1, 1048576L, 2048, (size_t)4096 * 2048);
    // Wt1 dead; transpose W6 into the same arena (stream-ordered)
    trans_bf16<<<dim3(625, 64), dim3(32, 8), 0, stream>>>(W6, WT16, 2048, 20000);
    mfma_gemm<1, 1, 0><<<dim3(8, 32), blk, 0, stream>>>(
        ACT1, WT2, b2, nullptr, ACT2, nullptr, 4096, 1024, 2048);
    mfma_gemm<1, 1, 1><<<dim3(4, 32), blk, 0, stream>>>(
        ACT2, WT3, b3, Z3F, Z3B, nullptr, 4096, 512, 1024);

    // ---- VQ: score GEMM with fused argmin, then gather + loss ----
    mfma_gemm<2, 0, 0><<<dim3(64, 32), blk, 0, stream>>>(
        Z3B, CBB, CN, nullptr, nullptr, PACKED, 4096, 8192, 512);
    quant_loss<<<dim3(2048), blk, 0, stream>>>(PACKED, CB, Z3F, qout, QB, PART);
    loss_final<<<dim3(1), blk, 0, stream>>>(PART, out);

    // ---- decoder ----
    mfma_gemm<1, 1, 0><<<dim3(8, 32), blk, 0, stream>>>(
        QB, WT4, b4, nullptr, ACT2, nullptr, 4096, 1024, 512);
    mfma_gemm<1, 1, 0><<<dim3(16, 32), blk, 0, stream>>>(
        ACT2, WT5, b5, nullptr, ACT1, nullptr, 4096, 2048, 1024);
    mfma_gemm<0, 0, 1><<<dim3(157, 32), blk, 0, stream>>>(
        ACT1, WT16, b6, xrec, nullptr, nullptr, 4096, 20000, 2048);
}

// Round 4
// 1304.616 us; speedup vs baseline: 8.9540x; 1.2435x over previous
//
#include <hip/hip_runtime.h>
#include <hip/hip_bf16.h>
#include <math.h>

// ---------------------------------------------------------------------------
// VQ-VAE forward. B=4096, G=20000, dims 2048/1024/512, K=8192 codes.
// Round 4: 256x256-tile 8-wave BK=64 GEMM with depth-2 counted-vmcnt prefetch
// (T3/T4 core: loads stay in flight across barriers, vmcnt(8) not 0) and T2
// LDS XOR-swizzle (slot ^= row&7, applied via pre-swizzled global source +
// swizzled ds_read; LDS dest stays linear) for GEMM1 + GEMM6. K padded
// 20000->20032. Small GEMMs + fused-argmin VQ stay on the 128^2 kernel.
// ---------------------------------------------------------------------------

typedef short v8s __attribute__((ext_vector_type(8)));
typedef float v4f __attribute__((ext_vector_type(4)));
typedef unsigned short u16;
typedef unsigned long long u64;

typedef const unsigned int __attribute__((address_space(1)))* as1p;
typedef unsigned int __attribute__((address_space(3)))* as3p;

__device__ __forceinline__ void gload_lds16(const void* g, void* l) {
    __builtin_amdgcn_global_load_lds((as1p)g, (as3p)l, 16, 0, 0);
}

__device__ __forceinline__ u16 f2b(float f) {
    return __builtin_bit_cast(u16, __float2bfloat16(f));
}

__device__ __forceinline__ unsigned int float_orderable(float f)
{
    unsigned int b = __float_as_uint(f);
    return (b & 0x80000000u) ? ~b : (b | 0x80000000u);
}

// ---------------------------------------------------------------------------
// 256x256 tile, 512 threads (8 waves = 2Mx4N), BK=64, double-buffered LDS
// (dynamic 128 KB), depth-2 tile prefetch with vmcnt(8), LDS slot-XOR swizzle.
// EPI: 0 = +bias, f32 store (col<N masked); 3 = raw f32 partials, K split
// over blockIdx.z, Cf += z*M*N. K % 64 == 0; M % 256 == 0; B rows padded to
// ceil(N/256)*256 readable. Per-wave output 128x64. nwg % 8 == 0 (XCD swz).
// ---------------------------------------------------------------------------
template<int EPI>
__global__ __launch_bounds__(512, 1) void gemm256(
    const u16* __restrict__ A, const u16* __restrict__ Bt,
    const float* __restrict__ bias, float* __restrict__ Cf,
    int M, int N, int K, int sA, int sB)
{
    extern __shared__ char lds[];   // [2][A 32K | B 32K] = 128 KB

    // bijective XCD swizzle (nwg % 8 == 0)
    const int gx = gridDim.x, gy = gridDim.y, gz = gridDim.z;
    const int nwg = gx * gy * gz;
    int flat = (blockIdx.z * gy + blockIdx.y) * gx + blockIdx.x;
    flat = (flat & 7) * (nwg >> 3) + (flat >> 3);
    const int bx = flat % gx;
    const int rem = flat / gx;
    const int by = rem % gy;
    const int bz = rem / gy;

    const int bm = by * 256;
    const int bn = bx * 256;

    const int tiles = K >> 6;
    int t0 = 0, t1 = tiles;
    if (EPI == 3) {
        const int qz = tiles / gz, rz = tiles % gz;
        t0 = bz * qz + (bz < rz ? bz : rz);
        t1 = t0 + qz + (bz < rz ? 1 : 0);
        Cf += (size_t)bz * ((size_t)M * N);
    }

    const int tid = threadIdx.x;
    const int wv = tid >> 6;
    const int ln = tid & 63;

    // ---- staging: per tile 8 gload_lds/lane (A x4, B x4), 1KB chunks/wave.
    // LDS linear; global source column pre-swizzled: slot ^= (row&7).
    const int srow = wv * 8 + (ln >> 3);
    const int scol = (((ln & 7) ^ ((ln >> 3) & 7))) * 8;
    const u16* Asrc = A + (size_t)(bm + srow) * sA + scol;
    const u16* Bsrc = Bt + (size_t)(bn + srow) * sB + scol;
    char* stA = lds + wv * 1024;
    char* stB = lds + 32768 + wv * 1024;

#define STAGE(p, kt)                                                          \
    {                                                                         \
        const u16* ap_ = Asrc + ((size_t)(kt) << 6);                          \
        const u16* bp_ = Bsrc + ((size_t)(kt) << 6);                          \
        char* la_ = stA + (p) * 65536;                                        \
        char* lb_ = stB + (p) * 65536;                                        \
        gload_lds16(ap_, la_);                                                \
        gload_lds16(ap_ + (size_t)64 * sA, la_ + 8192);                       \
        gload_lds16(ap_ + (size_t)128 * sA, la_ + 16384);                     \
        gload_lds16(ap_ + (size_t)192 * sA, la_ + 24576);                     \
        gload_lds16(bp_, lb_);                                                \
        gload_lds16(bp_ + (size_t)64 * sB, lb_ + 8192);                       \
        gload_lds16(bp_ + (size_t)128 * sB, lb_ + 16384);                     \
        gload_lds16(bp_ + (size_t)192 * sB, lb_ + 24576);                     \
    }

    // ---- fragment read bases (swizzled: byte col ^= (row&7)<<4)
    const int wr = wv >> 2, wc = wv & 3;
    const int fr = ln & 15;
    const int q = ln >> 4;
    const int swz = (fr & 7) << 4;
    const char* Afrag = lds + (size_t)(wr * 128 + fr) * 128;
    const char* Bfrag = lds + 32768 + (size_t)(wc * 64 + fr) * 128;

    v4f acc[8][4];
    #pragma unroll
    for (int m = 0; m < 8; ++m)
        #pragma unroll
        for (int n = 0; n < 4; ++n) acc[m][n] = (v4f)(0.f);

    auto compute = [&](int p) {
        const char* Ab = Afrag + p * 65536;
        const char* Bb = Bfrag + p * 65536;
        __builtin_amdgcn_s_setprio(1);
        #pragma unroll
        for (int kh = 0; kh < 2; ++kh) {
            const int cb = (kh * 64 + q * 16) ^ swz;
            v8s a[8], b[4];
            #pragma unroll
            for (int m = 0; m < 8; ++m) a[m] = *(const v8s*)(Ab + m * 2048 + cb);
            #pragma unroll
            for (int n = 0; n < 4; ++n) b[n] = *(const v8s*)(Bb + n * 2048 + cb);
            #pragma unroll
            for (int m = 0; m < 8; ++m)
                #pragma unroll
                for (int n = 0; n < 4; ++n)
                    acc[m][n] = __builtin_amdgcn_mfma_f32_16x16x32_bf16(
                        a[m], b[n], acc[m][n], 0, 0, 0);
        }
        __builtin_amdgcn_s_setprio(0);
    };

    // ---- main loop: depth-2 prefetch, vmcnt(8) (= one tile still in flight)
    STAGE(0, t0);
    STAGE(1, t0 + 1);
    int cur = 0;
    for (int t = t0; t < t1 - 2; ++t) {
        asm volatile("s_waitcnt vmcnt(8)" ::: "memory");
        __builtin_amdgcn_s_barrier();
        asm volatile("" ::: "memory");
        compute(cur);
        asm volatile("s_waitcnt lgkmcnt(0)" ::: "memory");
        __builtin_amdgcn_s_barrier();
        asm volatile("" ::: "memory");
        STAGE(cur, t + 2);
        cur ^= 1;
    }
    asm volatile("s_waitcnt vmcnt(8)" ::: "memory");
    __builtin_amdgcn_s_barrier();
    asm volatile("" ::: "memory");
    compute(cur);
    cur ^= 1;
    asm volatile("s_waitcnt vmcnt(0)" ::: "memory");
    __builtin_amdgcn_s_barrier();
    asm volatile("" ::: "memory");
    compute(cur);
#undef STAGE

    // ---- epilogue. C/D: col = ln&15, row = (ln>>4)*4 + r
    const int rb = q * 4;
    #pragma unroll
    for (int m = 0; m < 8; ++m) {
        const int row = bm + wr * 128 + m * 16 + rb;
        #pragma unroll
        for (int n = 0; n < 4; ++n) {
            const int col = bn + wc * 64 + n * 16 + fr;
            if (EPI == 3) {
                #pragma unroll
                for (int r = 0; r < 4; ++r)
                    Cf[(size_t)(row + r) * N + col] = acc[m][n][r];
            } else if (col < N) {
                const float bv = bias[col];
                #pragma unroll
                for (int r = 0; r < 4; ++r)
                    Cf[(size_t)(row + r) * N + col] = acc[m][n][r] + bv;
            }
        }
    }
}

// ---------------------------------------------------------------------------
// 128x128 m97-style kernel for the small/medium GEMMs + fused-argmin VQ.
// EPI: 0 = +bias, 1 = tanh(+bias), 2 = VQ argmin (score = bias - 2*acc,
// packed u64 atomicMin per row, no C write). WB/WF: bf16/f32 C writes.
// ---------------------------------------------------------------------------
template<int EPI, int WB, int WF>
__global__ __launch_bounds__(256, 2) void mfma_gemm(
    const u16* __restrict__ A, const u16* __restrict__ Bt,
    const float* __restrict__ bias, float* __restrict__ Cf,
    u16* __restrict__ Cb, u64* __restrict__ packed, int M, int N, int K)
{
    __shared__ u16 As[128 * 32];
    __shared__ u16 Bs[128 * 32];
    const int tid = threadIdx.x;
    const int wv = tid >> 6;
    const int ln = tid & 63;
    const int bm = blockIdx.y * 128;
    const int bn = blockIdx.x * 128;

    const int srow = wv * 32 + (ln >> 2);
    const int skel = (ln & 3) * 8;
    const u16* Ap0 = A + (size_t)(bm + srow) * K + skel;
    const u16* Ap1 = Ap0 + (size_t)16 * K;
    const u16* Bp0 = Bt + (size_t)(bn + srow) * K + skel;
    const u16* Bp1 = Bp0 + (size_t)16 * K;
    u16* lA0 = As + wv * 1024;
    u16* lA1 = lA0 + 512;
    u16* lB0 = Bs + wv * 1024;
    u16* lB1 = lB0 + 512;

    const int wr = wv >> 1, wc = wv & 1;
    const int fr = ln & 15;
    const int kg = (ln >> 4) * 8;
    const u16* Afp = As + (wr * 64 + fr) * 32 + kg;
    const u16* Bfp = Bs + (wc * 64 + fr) * 32 + kg;

    v4f acc[4][4];
    #pragma unroll
    for (int m = 0; m < 4; ++m)
        #pragma unroll
        for (int n = 0; n < 4; ++n) acc[m][n] = (v4f)(0.f);

    for (int k0 = 0; k0 < K; k0 += 32) {
        __syncthreads();
        gload_lds16(Ap0 + k0, lA0);
        gload_lds16(Ap1 + k0, lA1);
        gload_lds16(Bp0 + k0, lB0);
        gload_lds16(Bp1 + k0, lB1);
        __syncthreads();
        v8s a[4], b[4];
        #pragma unroll
        for (int m = 0; m < 4; ++m) a[m] = *(const v8s*)(Afp + m * 512);
        #pragma unroll
        for (int n = 0; n < 4; ++n) b[n] = *(const v8s*)(Bfp + n * 512);
        #pragma unroll
        for (int m = 0; m < 4; ++m)
            #pragma unroll
            for (int n = 0; n < 4; ++n)
                acc[m][n] = __builtin_amdgcn_mfma_f32_16x16x32_bf16(
                    a[m], b[n], acc[m][n], 0, 0, 0);
    }

    const int rb = (ln >> 4) * 4;

    if constexpr (EPI == 2) {
        __shared__ u64 smin[128];
        if (tid < 128) smin[tid] = ~0ull;
        __syncthreads();
        #pragma unroll
        for (int m = 0; m < 4; ++m) {
            #pragma unroll
            for (int r = 0; r < 4; ++r) {
                u64 best = ~0ull;
                #pragma unroll
                for (int n = 0; n < 4; ++n) {
                    const int col = bn + wc * 64 + n * 16 + fr;
                    const float s = fmaf(-2.f, acc[m][n][r], bias[col]);
                    const u64 pv =
                        ((u64)float_orderable(s) << 32) | (unsigned)col;
                    best = pv < best ? pv : best;
                }
                #pragma unroll
                for (int msk = 1; msk <= 8; msk <<= 1) {
                    const u64 o = __shfl_xor(best, msk);
                    best = o < best ? o : best;
                }
                if (fr == 0) atomicMin(&smin[wr * 64 + m * 16 + rb + r], best);
            }
        }
        __syncthreads();
        if (tid < 128) atomicMin(&packed[bm + tid], smin[tid]);
    } else {
        #pragma unroll
        for (int m = 0; m < 4; ++m) {
            const int row = bm + wr * 64 + m * 16 + rb;
            #pragma unroll
            for (int n = 0; n < 4; ++n) {
                const int col = bn + wc * 64 + n * 16 + fr;
                if (col < N) {
                    const float bv = bias[col];
                    #pragma unroll
                    for (int r = 0; r < 4; ++r) {
                        float v = acc[m][n][r] + bv;
                        if (EPI == 1) v = tanhf(v);
                        if (WF) Cf[(size_t)(row + r) * N + col] = v;
                        if (WB) Cb[(size_t)(row + r) * N + col] = f2b(v);
                    }
                }
            }
        }
    }
}

// out[i] = bf16(tanh(P0+P1+P2+P3+bias)), 8 elems/thread. cs = chunk stride.
__global__ __launch_bounds__(256) void reduce_tanh4(
    const float* __restrict__ P, const float* __restrict__ bias,
    u16* __restrict__ out, long n8, int N, size_t cs)
{
    const long stride = (long)gridDim.x * 256;
    for (long i = (long)blockIdx.x * 256 + threadIdx.x; i < n8; i += stride) {
        const size_t e0 = (size_t)i * 8;
        const int col = (int)(e0 & (size_t)(N - 1));
        float4 s0 = *(const float4*)(P + e0);
        float4 s1 = *(const float4*)(P + e0 + 4);
        #pragma unroll
        for (int c = 1; c < 4; ++c) {
            const float4 a = *(const float4*)(P + c * cs + e0);
            const float4 b = *(const float4*)(P + c * cs + e0 + 4);
            s0.x += a.x; s0.y += a.y; s0.z += a.z; s0.w += a.w;
            s1.x += b.x; s1.y += b.y; s1.z += b.z; s1.w += b.w;
        }
        const float4 bv0 = *(const float4*)(bias + col);
        const float4 bv1 = *(const float4*)(bias + col + 4);
        v8s o;
        o[0] = (short)f2b(tanhf(s0.x + bv0.x));
        o[1] = (short)f2b(tanhf(s0.y + bv0.y));
        o[2] = (short)f2b(tanhf(s0.z + bv0.z));
        o[3] = (short)f2b(tanhf(s0.w + bv0.w));
        o[4] = (short)f2b(tanhf(s1.x + bv1.x));
        o[5] = (short)f2b(tanhf(s1.y + bv1.y));
        o[6] = (short)f2b(tanhf(s1.z + bv1.z));
        o[7] = (short)f2b(tanhf(s1.w + bv1.w));
        *(v8s*)(out + e0) = o;
    }
}

// x [4096][20000] f32 -> xb [4096][20032] bf16, zero-padded. 1 block per row.
__global__ __launch_bounds__(256) void conv_pad_x(
    const float* __restrict__ in, u16* __restrict__ out)
{
    const int row = blockIdx.x;
    const float* src = in + (size_t)row * 20000;
    u16* dst = out + (size_t)row * 20032;
    for (int j = threadIdx.x; j < 2504; j += 256) {
        v8s o;
        if (j < 2500) {
            const float4 a = *(const float4*)(src + j * 8);
            const float4 b = *(const float4*)(src + j * 8 + 4);
            o[0] = (short)f2b(a.x); o[1] = (short)f2b(a.y);
            o[2] = (short)f2b(a.z); o[3] = (short)f2b(a.w);
            o[4] = (short)f2b(b.x); o[5] = (short)f2b(b.y);
            o[6] = (short)f2b(b.z); o[7] = (short)f2b(b.w);
        } else {
            o = (v8s)(short(0));
        }
        *(v8s*)(dst + j * 8) = o;
    }
}

// f32 -> bf16 elementwise, 8/thread. n8 = n/8.
__global__ __launch_bounds__(256) void conv_bf16(
    const float* __restrict__ in, u16* __restrict__ out, long n8)
{
    const long stride = (long)gridDim.x * 256;
    for (long i = (long)blockIdx.x * 256 + threadIdx.x; i < n8; i += stride) {
        const float4 a = ((const float4*)in)[i * 2];
        const float4 b = ((const float4*)in)[i * 2 + 1];
        v8s o;
        o[0] = (short)f2b(a.x); o[1] = (short)f2b(a.y);
        o[2] = (short)f2b(a.z); o[3] = (short)f2b(a.w);
        o[4] = (short)f2b(b.x); o[5] = (short)f2b(b.y);
        o[6] = (short)f2b(b.z); o[7] = (short)f2b(b.w);
        *(v8s*)(out + i * 8) = o;
    }
}

// W[K][N] f32 -> Wt[N][Kp] bf16, rows k>=K zero-filled (Kp >= K, grid.y
// covers ceil(Kp/32)). block (32,8).
__global__ __launch_bounds__(256) void trans_bf16p(
    const float* __restrict__ W, u16* __restrict__ Wt, int K, int N, int Kp)
{
    __shared__ float t[32][33];
    const int tx = threadIdx.x, ty = threadIdx.y;
    const int n0 = blockIdx.x * 32, k0 = blockIdx.y * 32;
    #pragma unroll
    for (int i = 0; i < 32; i += 8) {
        const int n = n0 + tx;
        const int k = k0 + ty + i;
        t[ty + i][tx] = (n < N && k < K) ? W[(size_t)k * N + n] : 0.f;
    }
    __syncthreads();
    #pragma unroll
    for (int i = 0; i < 32; i += 8) {
        const int n = n0 + ty + i;
        if (n < N) Wt[(size_t)n * Kp + k0 + tx] = f2b(t[tx][ty + i]);
    }
}

// cnorm[k] = ||codebook[k]||^2 (f32), one wave per row.
__global__ __launch_bounds__(64) void cnorm_k(
    const float* __restrict__ CB, float* __restrict__ cn)
{
    const float* row = CB + (size_t)blockIdx.x * 512;
    float s = 0.f;
    #pragma unroll
    for (int u = 0; u < 8; ++u) {
        const float v = row[threadIdx.x + 64 * u];
        s = fmaf(v, v, s);
    }
    #pragma unroll
    for (int m = 32; m; m >>= 1) s += __shfl_down(s, m);
    if (threadIdx.x == 0) cn[blockIdx.x] = s;
}

__global__ void init_packed(u64* __restrict__ p)
{
    p[blockIdx.x * 256 + threadIdx.x] = ~0ull;
}

// gather q rows -> qout (f32, d_out) + qb (bf16, decoder input);
// block partials of sum((q-z)^2) in f64.
__global__ __launch_bounds__(256) void quant_loss(
    const u64* __restrict__ packed, const float* __restrict__ CB,
    const float* __restrict__ Z, float* __restrict__ qout,
    u16* __restrict__ qb, double* __restrict__ partials)
{
    const int gid = blockIdx.x * 256 + threadIdx.x;
    const int i = gid >> 7;
    const int j = (gid & 127) << 2;
    const int k = (int)(packed[i] & 0xffffffffull);
    const float4 c = *(const float4*)(CB + (size_t)k * 512 + j);
    const float4 z = *(const float4*)(Z + (size_t)i * 512 + j);
    const size_t o = (size_t)i * 512 + j;
    qout[o + 0] = c.x; qout[o + 1] = c.y; qout[o + 2] = c.z; qout[o + 3] = c.w;
    qb[o + 0] = f2b(c.x); qb[o + 1] = f2b(c.y);
    qb[o + 2] = f2b(c.z); qb[o + 3] = f2b(c.w);
    const float d0 = c.x - z.x, d1 = c.y - z.y, d2 = c.z - z.z, d3 = c.w - z.w;
    float local = d0 * d0 + d1 * d1 + d2 * d2 + d3 * d3;
    #pragma unroll
    for (int m = 32; m; m >>= 1) local += __shfl_down(local, m);
    __shared__ float wsum[4];
    if ((threadIdx.x & 63) == 0) wsum[threadIdx.x >> 6] = local;
    __syncthreads();
    if (threadIdx.x == 0)
        partials[blockIdx.x] = (double)wsum[0] + (double)wsum[1] +
                               (double)wsum[2] + (double)wsum[3];
}

__global__ __launch_bounds__(256) void loss_final(
    const double* __restrict__ partials, float* __restrict__ out)
{
    double s = 0.0;
    for (int u = threadIdx.x; u < 2048; u += 256) s += partials[u];
    #pragma unroll
    for (int m = 32; m; m >>= 1) s += __shfl_down(s, m);
    __shared__ double ws[4];
    if ((threadIdx.x & 63) == 0) ws[threadIdx.x >> 6] = s;
    __syncthreads();
    if (threadIdx.x == 0)
        out[0] = (float)(1.25 * (ws[0] + ws[1] + ws[2] + ws[3]) / 2097152.0);
}

extern "C" void kernel_launch(void* const* d_in, const int* in_sizes, int n_in,
                              void* d_out, int out_size, void* d_ws, size_t ws_size,
                              hipStream_t stream)
{
    const float* x  = (const float*)d_in[0];
    const float* W1 = (const float*)d_in[1];
    const float* b1 = (const float*)d_in[2];
    const float* W2 = (const float*)d_in[3];
    const float* b2 = (const float*)d_in[4];
    const float* W3 = (const float*)d_in[5];
    const float* b3 = (const float*)d_in[6];
    const float* CB = (const float*)d_in[7];
    const float* W4 = (const float*)d_in[8];
    const float* b4 = (const float*)d_in[9];
    const float* W5 = (const float*)d_in[10];
    const float* b5 = (const float*)d_in[11];
    const float* W6 = (const float*)d_in[12];
    const float* b6 = (const float*)d_in[13];

    float* out  = (float*)d_out;
    float* xrec = out + 1;
    float* qout = out + 1 + (size_t)4096 * 20000;

    // scratch inside d_out's x_recon region (dead until final GEMM):
    u16*   xb    = (u16*)((char*)d_out + 16);                 // [4096][20032] bf16
    float* PART1 = (float*)((char*)d_out + 164102160);        // 4x[4096][2048] f32

    char* ws = (char*)d_ws;
    u16* WT16 = (u16*)(ws + 0);           // Wt1 [2048][20032] / Wt6 [20224][2048]
    u16* WT2  = (u16*)(ws + 82837504);    // [1024][2048]
    u16* WT3  = (u16*)(ws + 87031808);    // [512][1024]
    u16* CBB  = (u16*)(ws + 88080384);    // [8192][512]
    u16* WT4  = (u16*)(ws + 96468992);    // [1024][512]
    u16* WT5  = (u16*)(ws + 97517568);    // [2048][1024]
    u16* ACT1 = (u16*)(ws + 101711872);   // [4096][2048] z1, later h2
    u16* ACT2 = (u16*)(ws + 118489088);   // [4096][1024] z2, later h1
    float* Z3F = (float*)(ws + 126877696); // [4096][512]
    u16* Z3B  = (u16*)(ws + 135266304);   // [4096][512]
    u16* QB   = (u16*)(ws + 139460608);   // [4096][512]
    float* CN = (float*)(ws + 143654912);
    u64* PACKED = (u64*)(ws + 143687680);
    double* PART = (double*)(ws + 143720448);

    const dim3 blk(256);

    // ---- precompute: bf16 conversions + weight transposes ----
    conv_pad_x<<<dim3(4096), blk, 0, stream>>>(x, xb);
    conv_bf16<<<dim3(2048), blk, 0, stream>>>(CB, CBB, 524288L);
    trans_bf16p<<<dim3(64, 626), dim3(32, 8), 0, stream>>>(W1, WT16, 20000, 2048, 20032);
    trans_bf16p<<<dim3(32, 64),  dim3(32, 8), 0, stream>>>(W2, WT2, 2048, 1024, 2048);
    trans_bf16p<<<dim3(16, 32),  dim3(32, 8), 0, stream>>>(W3, WT3, 1024, 512, 1024);
    trans_bf16p<<<dim3(32, 16),  dim3(32, 8), 0, stream>>>(W4, WT4, 512, 1024, 512);
    trans_bf16p<<<dim3(64, 32),  dim3(32, 8), 0, stream>>>(W5, WT5, 1024, 2048, 1024);
    cnorm_k<<<dim3(8192), dim3(64), 0, stream>>>(CB, CN);
    init_packed<<<dim3(16), blk, 0, stream>>>(PACKED);

    // ---- encoder ----
    // GEMM1: 256^2 tile, split-K over 4 chunks (8*16*4 = 512 blocks)
    gemm256<3><<<dim3(8, 16, 4), dim3(512), 131072, stream>>>(
        xb, WT16, nullptr, PART1, 4096, 2048, 20032, 20032, 20032);
    reduce_tanh4<<<dim3(4096), blk, 0, stream>>>(
        PART1, b1, ACT1, 1048576L, 2048, (size_t)4096 * 2048);
    // Wt1 dead; transpose W6 into the same arena (stream-ordered)
    trans_bf16p<<<dim3(625, 64), dim3(32, 8), 0, stream>>>(W6, WT16, 2048, 20000, 2048);
    mfma_gemm<1, 1, 0><<<dim3(8, 32), blk, 0, stream>>>(
        ACT1, WT2, b2, nullptr, ACT2, nullptr, 4096, 1024, 2048);
    mfma_gemm<1, 1, 1><<<dim3(4, 32), blk, 0, stream>>>(
        ACT2, WT3, b3, Z3F, Z3B, nullptr, 4096, 512, 1024);

    // ---- VQ: score GEMM with fused argmin, then gather + loss ----
    mfma_gemm<2, 0, 0><<<dim3(64, 32), blk, 0, stream>>>(
        Z3B, CBB, CN, nullptr, nullptr, PACKED, 4096, 8192, 512);
    quant_loss<<<dim3(2048), blk, 0, stream>>>(PACKED, CB, Z3F, qout, QB, PART);
    loss_final<<<dim3(1), blk, 0, stream>>>(PART, out);

    // ---- decoder ----
    mfma_gemm<1, 1, 0><<<dim3(8, 32), blk, 0, stream>>>(
        QB, WT4, b4, nullptr, ACT2, nullptr, 4096, 1024, 512);
    mfma_gemm<1, 1, 0><<<dim3(16, 32), blk, 0, stream>>>(
        ACT2, WT5, b5, nullptr, ACT1, nullptr, 4096, 2048, 1024);
    // GEMM6: 256^2 tile, grid 79x16 = 1264 blocks (padded Wt6 rows readable)
    gemm256<0><<<dim3(79, 16), dim3(512), 131072, stream>>>(
        ACT1, WT16, b6, xrec, 4096, 20000, 2048, 2048, 2048);
}

// Round 5
// 1211.332 us; speedup vs baseline: 9.6435x; 1.0770x over previous
//
#include <hip/hip_runtime.h>
#include <hip/hip_bf16.h>
#include <math.h>

// ---------------------------------------------------------------------------
// VQ-VAE forward. B=4096, G=20000, dims 2048/1024/512, K=8192 codes.
// Round 5: gemm256 K-loop rebuilt as a 4-phase interleaved schedule (T3+T4):
// per K-tile phases (mh0,k0)(mh0,k1)(mh1,k0)(mh1,k1); B-frags persist in regs
// so B-rows + A-rows{j0,j2} die after phase1 -> stage tile t+2 mid-compute
// (mid-6 after p1 barrier, end-2 after p3 barrier). Counted vmcnt(10/14) from
// FIFO algebra; never 0 in main loop. T2 swizzle kept (conflicts were 0).
// ---------------------------------------------------------------------------

typedef short v8s __attribute__((ext_vector_type(8)));
typedef float v4f __attribute__((ext_vector_type(4)));
typedef unsigned short u16;
typedef unsigned long long u64;

typedef const unsigned int __attribute__((address_space(1)))* as1p;
typedef unsigned int __attribute__((address_space(3)))* as3p;

__device__ __forceinline__ void gload_lds16(const void* g, void* l) {
    __builtin_amdgcn_global_load_lds((as1p)g, (as3p)l, 16, 0, 0);
}

__device__ __forceinline__ u16 f2b(float f) {
    return __builtin_bit_cast(u16, __float2bfloat16(f));
}

__device__ __forceinline__ unsigned int float_orderable(float f)
{
    unsigned int b = __float_as_uint(f);
    return (b & 0x80000000u) ? ~b : (b | 0x80000000u);
}

#define FENCE asm volatile("" ::: "memory")

// ---------------------------------------------------------------------------
// 256x256 tile, 512 threads (8 waves = 2Mx4N), BK=64, double-buffered LDS
// (dynamic 128 KB), 4-phase interleaved K-loop, LDS slot-XOR swizzle.
// EPI: 0 = +bias f32 store (col<N masked); 3 = raw f32 partials, K split over
// blockIdx.z. K % 64 == 0; M % 256 == 0; Bt rows padded readable; >=2 K-tiles
// per block required. nwg % 8 == 0 (XCD swizzle).
// ---------------------------------------------------------------------------
template<int EPI>
__global__ __launch_bounds__(512, 2) void gemm256(
    const u16* __restrict__ A, const u16* __restrict__ Bt,
    const float* __restrict__ bias, float* __restrict__ Cf,
    int M, int N, int K, int sA, int sB)
{
    extern __shared__ char lds[];   // [2][A 32K | B 32K] = 128 KB

    // bijective XCD swizzle (nwg % 8 == 0)
    const int gx = gridDim.x, gy = gridDim.y, gz = gridDim.z;
    const int nwg = gx * gy * gz;
    int flat = (blockIdx.z * gy + blockIdx.y) * gx + blockIdx.x;
    flat = (flat & 7) * (nwg >> 3) + (flat >> 3);
    const int bx = flat % gx;
    const int rem = flat / gx;
    const int by = rem % gy;
    const int bz = rem / gy;

    const int bm = by * 256;
    const int bn = bx * 256;

    const int tiles = K >> 6;
    int t0 = 0, t1 = tiles;
    if (EPI == 3) {
        const int qz = tiles / gz, rz = tiles % gz;
        t0 = bz * qz + (bz < rz ? bz : rz);
        t1 = t0 + qz + (bz < rz ? 1 : 0);
        Cf += (size_t)bz * ((size_t)M * N);
    }

    const int tid = threadIdx.x;
    const int wv = tid >> 6;
    const int ln = tid & 63;

    // staging: wave wv stages 1KB chunks; load-unit J covers rows [J*64+wv*8).
    // LDS linear; global source column pre-swizzled: slot ^= (row&7).
    const int srow = wv * 8 + (ln >> 3);
    const int scol = (((ln & 7) ^ ((ln >> 3) & 7))) * 8;
    const u16* Asrc = A + (size_t)(bm + srow) * sA + scol;
    const u16* Bsrc = Bt + (size_t)(bn + srow) * sB + scol;
    char* stA = lds + wv * 1024;
    char* stB = lds + 32768 + wv * 1024;

#define STG_A(P, KT, J)                                                       \
    gload_lds16(Asrc + ((size_t)(KT) << 6) + (size_t)(J) * 64 * sA,           \
                stA + (P) * 65536 + (J) * 8192)
#define STG_B(P, KT, J)                                                       \
    gload_lds16(Bsrc + ((size_t)(KT) << 6) + (size_t)(J) * 64 * sB,           \
                stB + (P) * 65536 + (J) * 8192)
// mid-6: all B units + A units {0,2} (rows 0-63,128-191 = per-wave mh0 rows)
#define STAGE_MID(P, KT)                                                      \
    { STG_B(P, KT, 0); STG_B(P, KT, 1); STG_B(P, KT, 2); STG_B(P, KT, 3);     \
      STG_A(P, KT, 0); STG_A(P, KT, 2); }
// end-2: A units {1,3} (rows 64-127,192-255 = per-wave mh1 rows)
#define STAGE_END(P, KT)                                                      \
    { STG_A(P, KT, 1); STG_A(P, KT, 3); }

    // fragment read bases (swizzled: byte col ^= (row&7)<<4)
    const int wr = wv >> 2, wc = wv & 3;
    const int fr = ln & 15;
    const int q = ln >> 4;
    const int swz = (fr & 7) << 4;
    const char* Afrag = lds + (size_t)(wr * 128 + fr) * 128;
    const char* Bfrag = lds + 32768 + (size_t)(wc * 64 + fr) * 128;

    v4f acc[8][4];
    #pragma unroll
    for (int m = 0; m < 8; ++m)
        #pragma unroll
        for (int n = 0; n < 4; ++n) acc[m][n] = (v4f)(0.f);

    v8s b0[4], b1[4];

// one phase: optional B-frag load, 4 A-frag ds_reads, 16 MFMA. MH is a
// literal token so every acc index is compile-time (no scratch).
#define QUAD(PP, KH, MH, BARR, LOADB)                                         \
    {                                                                         \
        const char* Ab_ = Afrag + (PP) * 65536;                               \
        const int cb_ = ((KH) * 64 + q * 16) ^ swz;                           \
        if (LOADB) {                                                          \
            const char* Bb_ = Bfrag + (PP) * 65536;                           \
            _Pragma("unroll")                                                 \
            for (int n = 0; n < 4; ++n)                                       \
                BARR[n] = *(const v8s*)(Bb_ + n * 2048 + cb_);                \
        }                                                                     \
        v8s a_[4];                                                            \
        _Pragma("unroll")                                                     \
        for (int m = 0; m < 4; ++m)                                           \
            a_[m] = *(const v8s*)(Ab_ + ((MH) * 4 + m) * 2048 + cb_);         \
        __builtin_amdgcn_s_setprio(1);                                        \
        _Pragma("unroll")                                                     \
        for (int m = 0; m < 4; ++m)                                           \
            _Pragma("unroll")                                                 \
            for (int n = 0; n < 4; ++n)                                       \
                acc[(MH) * 4 + m][n] =                                        \
                    __builtin_amdgcn_mfma_f32_16x16x32_bf16(                  \
                        a_[m], BARR[n], acc[(MH) * 4 + m][n], 0, 0, 0);       \
        __builtin_amdgcn_s_setprio(0);                                        \
    }

    // prologue: stage first two tiles (mid/end order fixes the vmcnt FIFO)
    STAGE_MID(0, t0); STAGE_END(0, t0);
    STAGE_MID(1, t0 + 1); STAGE_END(1, t0 + 1);

    int cur = 0;
    // main loop: tiles with full prefetch of t+2
    for (int t = t0; t < t1 - 2; ++t) {
        // entry: need tile t mid-6 landed; younger = own end2 + t+1's 8 = 10
        asm volatile("s_waitcnt vmcnt(10)" ::: "memory");
        FENCE; __builtin_amdgcn_s_barrier(); FENCE;
        QUAD(cur, 0, 0, b0, true);
        QUAD(cur, 1, 0, b1, true);
        FENCE; __builtin_amdgcn_s_barrier(); FENCE;   // B + A-mh0 rows dead
        STAGE_MID(cur, t + 2);
        // need tile t end-2 landed; younger = t+1's 8 + t+2's mid-6 = 14
        asm volatile("s_waitcnt vmcnt(14)" ::: "memory");
        QUAD(cur, 0, 1, b0, false);
        QUAD(cur, 1, 1, b1, false);
        FENCE; __builtin_amdgcn_s_barrier(); FENCE;   // A-mh1 rows dead
        STAGE_END(cur, t + 2);
        cur ^= 1;
    }
    // penultimate tile (no staging): waits (10, 8)
    asm volatile("s_waitcnt vmcnt(10)" ::: "memory");
    FENCE; __builtin_amdgcn_s_barrier(); FENCE;
    QUAD(cur, 0, 0, b0, true);
    QUAD(cur, 1, 0, b1, true);
    FENCE; __builtin_amdgcn_s_barrier(); FENCE;
    asm volatile("s_waitcnt vmcnt(8)" ::: "memory");
    QUAD(cur, 0, 1, b0, false);
    QUAD(cur, 1, 1, b1, false);
    cur ^= 1;
    // last tile: waits (2, 0)
    asm volatile("s_waitcnt vmcnt(2)" ::: "memory");
    FENCE; __builtin_amdgcn_s_barrier(); FENCE;
    QUAD(cur, 0, 0, b0, true);
    QUAD(cur, 1, 0, b1, true);
    asm volatile("s_waitcnt vmcnt(0)" ::: "memory");
    QUAD(cur, 0, 1, b0, false);
    QUAD(cur, 1, 1, b1, false);
#undef QUAD
#undef STAGE_MID
#undef STAGE_END
#undef STG_A
#undef STG_B

    // epilogue. C/D: col = ln&15, row = (ln>>4)*4 + r
    const int rb = q * 4;
    #pragma unroll
    for (int m = 0; m < 8; ++m) {
        const int row = bm + wr * 128 + m * 16 + rb;
        #pragma unroll
        for (int n = 0; n < 4; ++n) {
            const int col = bn + wc * 64 + n * 16 + fr;
            if (EPI == 3) {
                #pragma unroll
                for (int r = 0; r < 4; ++r)
                    Cf[(size_t)(row + r) * N + col] = acc[m][n][r];
            } else if (col < N) {
                const float bv = bias[col];
                #pragma unroll
                for (int r = 0; r < 4; ++r)
                    Cf[(size_t)(row + r) * N + col] = acc[m][n][r] + bv;
            }
        }
    }
}

// ---------------------------------------------------------------------------
// 128x128 m97-style kernel for the small/medium GEMMs + fused-argmin VQ.
// EPI: 0 = +bias, 1 = tanh(+bias), 2 = VQ argmin (score = bias - 2*acc,
// packed u64 atomicMin per row, no C write). WB/WF: bf16/f32 C writes.
// ---------------------------------------------------------------------------
template<int EPI, int WB, int WF>
__global__ __launch_bounds__(256, 2) void mfma_gemm(
    const u16* __restrict__ A, const u16* __restrict__ Bt,
    const float* __restrict__ bias, float* __restrict__ Cf,
    u16* __restrict__ Cb, u64* __restrict__ packed, int M, int N, int K)
{
    __shared__ u16 As[128 * 32];
    __shared__ u16 Bs[128 * 32];
    const int tid = threadIdx.x;
    const int wv = tid >> 6;
    const int ln = tid & 63;
    const int bm = blockIdx.y * 128;
    const int bn = blockIdx.x * 128;

    const int srow = wv * 32 + (ln >> 2);
    const int skel = (ln & 3) * 8;
    const u16* Ap0 = A + (size_t)(bm + srow) * K + skel;
    const u16* Ap1 = Ap0 + (size_t)16 * K;
    const u16* Bp0 = Bt + (size_t)(bn + srow) * K + skel;
    const u16* Bp1 = Bp0 + (size_t)16 * K;
    u16* lA0 = As + wv * 1024;
    u16* lA1 = lA0 + 512;
    u16* lB0 = Bs + wv * 1024;
    u16* lB1 = lB0 + 512;

    const int wr = wv >> 1, wc = wv & 1;
    const int fr = ln & 15;
    const int kg = (ln >> 4) * 8;
    const u16* Afp = As + (wr * 64 + fr) * 32 + kg;
    const u16* Bfp = Bs + (wc * 64 + fr) * 32 + kg;

    v4f acc[4][4];
    #pragma unroll
    for (int m = 0; m < 4; ++m)
        #pragma unroll
        for (int n = 0; n < 4; ++n) acc[m][n] = (v4f)(0.f);

    for (int k0 = 0; k0 < K; k0 += 32) {
        __syncthreads();
        gload_lds16(Ap0 + k0, lA0);
        gload_lds16(Ap1 + k0, lA1);
        gload_lds16(Bp0 + k0, lB0);
        gload_lds16(Bp1 + k0, lB1);
        __syncthreads();
        v8s a[4], b[4];
        #pragma unroll
        for (int m = 0; m < 4; ++m) a[m] = *(const v8s*)(Afp + m * 512);
        #pragma unroll
        for (int n = 0; n < 4; ++n) b[n] = *(const v8s*)(Bfp + n * 512);
        #pragma unroll
        for (int m = 0; m < 4; ++m)
            #pragma unroll
            for (int n = 0; n < 4; ++n)
                acc[m][n] = __builtin_amdgcn_mfma_f32_16x16x32_bf16(
                    a[m], b[n], acc[m][n], 0, 0, 0);
    }

    const int rb = (ln >> 4) * 4;

    if constexpr (EPI == 2) {
        __shared__ u64 smin[128];
        if (tid < 128) smin[tid] = ~0ull;
        __syncthreads();
        #pragma unroll
        for (int m = 0; m < 4; ++m) {
            #pragma unroll
            for (int r = 0; r < 4; ++r) {
                u64 best = ~0ull;
                #pragma unroll
                for (int n = 0; n < 4; ++n) {
                    const int col = bn + wc * 64 + n * 16 + fr;
                    const float s = fmaf(-2.f, acc[m][n][r], bias[col]);
                    const u64 pv =
                        ((u64)float_orderable(s) << 32) | (unsigned)col;
                    best = pv < best ? pv : best;
                }
                #pragma unroll
                for (int msk = 1; msk <= 8; msk <<= 1) {
                    const u64 o = __shfl_xor(best, msk);
                    best = o < best ? o : best;
                }
                if (fr == 0) atomicMin(&smin[wr * 64 + m * 16 + rb + r], best);
            }
        }
        __syncthreads();
        if (tid < 128) atomicMin(&packed[bm + tid], smin[tid]);
    } else {
        #pragma unroll
        for (int m = 0; m < 4; ++m) {
            const int row = bm + wr * 64 + m * 16 + rb;
            #pragma unroll
            for (int n = 0; n < 4; ++n) {
                const int col = bn + wc * 64 + n * 16 + fr;
                if (col < N) {
                    const float bv = bias[col];
                    #pragma unroll
                    for (int r = 0; r < 4; ++r) {
                        float v = acc[m][n][r] + bv;
                        if (EPI == 1) v = tanhf(v);
                        if (WF) Cf[(size_t)(row + r) * N + col] = v;
                        if (WB) Cb[(size_t)(row + r) * N + col] = f2b(v);
                    }
                }
            }
        }
    }
}

// out[i] = bf16(tanh(P0+P1+P2+P3+bias)), 8 elems/thread. cs = chunk stride.
__global__ __launch_bounds__(256) void reduce_tanh4(
    const float* __restrict__ P, const float* __restrict__ bias,
    u16* __restrict__ out, long n8, int N, size_t cs)
{
    const long stride = (long)gridDim.x * 256;
    for (long i = (long)blockIdx.x * 256 + threadIdx.x; i < n8; i += stride) {
        const size_t e0 = (size_t)i * 8;
        const int col = (int)(e0 & (size_t)(N - 1));
        float4 s0 = *(const float4*)(P + e0);
        float4 s1 = *(const float4*)(P + e0 + 4);
        #pragma unroll
        for (int c = 1; c < 4; ++c) {
            const float4 a = *(const float4*)(P + c * cs + e0);
            const float4 b = *(const float4*)(P + c * cs + e0 + 4);
            s0.x += a.x; s0.y += a.y; s0.z += a.z; s0.w += a.w;
            s1.x += b.x; s1.y += b.y; s1.z += b.z; s1.w += b.w;
        }
        const float4 bv0 = *(const float4*)(bias + col);
        const float4 bv1 = *(const float4*)(bias + col + 4);
        v8s o;
        o[0] = (short)f2b(tanhf(s0.x + bv0.x));
        o[1] = (short)f2b(tanhf(s0.y + bv0.y));
        o[2] = (short)f2b(tanhf(s0.z + bv0.z));
        o[3] = (short)f2b(tanhf(s0.w + bv0.w));
        o[4] = (short)f2b(tanhf(s1.x + bv1.x));
        o[5] = (short)f2b(tanhf(s1.y + bv1.y));
        o[6] = (short)f2b(tanhf(s1.z + bv1.z));
        o[7] = (short)f2b(tanhf(s1.w + bv1.w));
        *(v8s*)(out + e0) = o;
    }
}

// x [4096][20000] f32 -> xb [4096][20032] bf16, zero-padded. 1 block per row.
__global__ __launch_bounds__(256) void conv_pad_x(
    const float* __restrict__ in, u16* __restrict__ out)
{
    const int row = blockIdx.x;
    const float* src = in + (size_t)row * 20000;
    u16* dst = out + (size_t)row * 20032;
    for (int j = threadIdx.x; j < 2504; j += 256) {
        v8s o;
        if (j < 2500) {
            const float4 a = *(const float4*)(src + j * 8);
            const float4 b = *(const float4*)(src + j * 8 + 4);
            o[0] = (short)f2b(a.x); o[1] = (short)f2b(a.y);
            o[2] = (short)f2b(a.z); o[3] = (short)f2b(a.w);
            o[4] = (short)f2b(b.x); o[5] = (short)f2b(b.y);
            o[6] = (short)f2b(b.z); o[7] = (short)f2b(b.w);
        } else {
            o = (v8s)(short(0));
        }
        *(v8s*)(dst + j * 8) = o;
    }
}

// f32 -> bf16 elementwise, 8/thread. n8 = n/8.
__global__ __launch_bounds__(256) void conv_bf16(
    const float* __restrict__ in, u16* __restrict__ out, long n8)
{
    const long stride = (long)gridDim.x * 256;
    for (long i = (long)blockIdx.x * 256 + threadIdx.x; i < n8; i += stride) {
        const float4 a = ((const float4*)in)[i * 2];
        const float4 b = ((const float4*)in)[i * 2 + 1];
        v8s o;
        o[0] = (short)f2b(a.x); o[1] = (short)f2b(a.y);
        o[2] = (short)f2b(a.z); o[3] = (short)f2b(a.w);
        o[4] = (short)f2b(b.x); o[5] = (short)f2b(b.y);
        o[6] = (short)f2b(b.z); o[7] = (short)f2b(b.w);
        *(v8s*)(out + i * 8) = o;
    }
}

// W[K][N] f32 -> Wt[N][Kp] bf16, rows k>=K zero-filled. block (32,8).
__global__ __launch_bounds__(256) void trans_bf16p(
    const float* __restrict__ W, u16* __restrict__ Wt, int K, int N, int Kp)
{
    __shared__ float t[32][33];
    const int tx = threadIdx.x, ty = threadIdx.y;
    const int n0 = blockIdx.x * 32, k0 = blockIdx.y * 32;
    #pragma unroll
    for (int i = 0; i < 32; i += 8) {
        const int n = n0 + tx;
        const int k = k0 + ty + i;
        t[ty + i][tx] = (n < N && k < K) ? W[(size_t)k * N + n] : 0.f;
    }
    __syncthreads();
    #pragma unroll
    for (int i = 0; i < 32; i += 8) {
        const int n = n0 + ty + i;
        if (n < N) Wt[(size_t)n * Kp + k0 + tx] = f2b(t[tx][ty + i]);
    }
}

// cnorm[k] = ||codebook[k]||^2 (f32), one wave per row.
__global__ __launch_bounds__(64) void cnorm_k(
    const float* __restrict__ CB, float* __restrict__ cn)
{
    const float* row = CB + (size_t)blockIdx.x * 512;
    float s = 0.f;
    #pragma unroll
    for (int u = 0; u < 8; ++u) {
        const float v = row[threadIdx.x + 64 * u];
        s = fmaf(v, v, s);
    }
    #pragma unroll
    for (int m = 32; m; m >>= 1) s += __shfl_down(s, m);
    if (threadIdx.x == 0) cn[blockIdx.x] = s;
}

__global__ void init_packed(u64* __restrict__ p)
{
    p[blockIdx.x * 256 + threadIdx.x] = ~0ull;
}

// gather q rows -> qout (f32, d_out) + qb (bf16, decoder input);
// block partials of sum((q-z)^2) in f64.
__global__ __launch_bounds__(256) void quant_loss(
    const u64* __restrict__ packed, const float* __restrict__ CB,
    const float* __restrict__ Z, float* __restrict__ qout,
    u16* __restrict__ qb, double* __restrict__ partials)
{
    const int gid = blockIdx.x * 256 + threadIdx.x;
    const int i = gid >> 7;
    const int j = (gid & 127) << 2;
    const int k = (int)(packed[i] & 0xffffffffull);
    const float4 c = *(const float4*)(CB + (size_t)k * 512 + j);
    const float4 z = *(const float4*)(Z + (size_t)i * 512 + j);
    const size_t o = (size_t)i * 512 + j;
    qout[o + 0] = c.x; qout[o + 1] = c.y; qout[o + 2] = c.z; qout[o + 3] = c.w;
    qb[o + 0] = f2b(c.x); qb[o + 1] = f2b(c.y);
    qb[o + 2] = f2b(c.z); qb[o + 3] = f2b(c.w);
    const float d0 = c.x - z.x, d1 = c.y - z.y, d2 = c.z - z.z, d3 = c.w - z.w;
    float local = d0 * d0 + d1 * d1 + d2 * d2 + d3 * d3;
    #pragma unroll
    for (int m = 32; m; m >>= 1) local += __shfl_down(local, m);
    __shared__ float wsum[4];
    if ((threadIdx.x & 63) == 0) wsum[threadIdx.x >> 6] = local;
    __syncthreads();
    if (threadIdx.x == 0)
        partials[blockIdx.x] = (double)wsum[0] + (double)wsum[1] +
                               (double)wsum[2] + (double)wsum[3];
}

__global__ __launch_bounds__(256) void loss_final(
    const double* __restrict__ partials, float* __restrict__ out)
{
    double s = 0.0;
    for (int u = threadIdx.x; u < 2048; u += 256) s += partials[u];
    #pragma unroll
    for (int m = 32; m; m >>= 1) s += __shfl_down(s, m);
    __shared__ double ws[4];
    if ((threadIdx.x & 63) == 0) ws[threadIdx.x >> 6] = s;
    __syncthreads();
    if (threadIdx.x == 0)
        out[0] = (float)(1.25 * (ws[0] + ws[1] + ws[2] + ws[3]) / 2097152.0);
}

extern "C" void kernel_launch(void* const* d_in, const int* in_sizes, int n_in,
                              void* d_out, int out_size, void* d_ws, size_t ws_size,
                              hipStream_t stream)
{
    const float* x  = (const float*)d_in[0];
    const float* W1 = (const float*)d_in[1];
    const float* b1 = (const float*)d_in[2];
    const float* W2 = (const float*)d_in[3];
    const float* b2 = (const float*)d_in[4];
    const float* W3 = (const float*)d_in[5];
    const float* b3 = (const float*)d_in[6];
    const float* CB = (const float*)d_in[7];
    const float* W4 = (const float*)d_in[8];
    const float* b4 = (const float*)d_in[9];
    const float* W5 = (const float*)d_in[10];
    const float* b5 = (const float*)d_in[11];
    const float* W6 = (const float*)d_in[12];
    const float* b6 = (const float*)d_in[13];

    float* out  = (float*)d_out;
    float* xrec = out + 1;
    float* qout = out + 1 + (size_t)4096 * 20000;

    // scratch inside d_out's x_recon region (dead until final GEMM):
    u16*   xb    = (u16*)((char*)d_out + 16);                 // [4096][20032] bf16
    float* PART1 = (float*)((char*)d_out + 164102160);        // 4x[4096][2048] f32

    char* ws = (char*)d_ws;
    u16* WT16 = (u16*)(ws + 0);           // Wt1 [2048][20032] / Wt6 [20224][2048]
    u16* WT2  = (u16*)(ws + 82837504);    // [1024][2048]
    u16* WT3  = (u16*)(ws + 87031808);    // [512][1024]
    u16* CBB  = (u16*)(ws + 88080384);    // [8192][512]
    u16* WT4  = (u16*)(ws + 96468992);    // [1024][512]
    u16* WT5  = (u16*)(ws + 97517568);    // [2048][1024]
    u16* ACT1 = (u16*)(ws + 101711872);   // [4096][2048] z1, later h2
    u16* ACT2 = (u16*)(ws + 118489088);   // [4096][1024] z2, later h1
    float* Z3F = (float*)(ws + 126877696); // [4096][512]
    u16* Z3B  = (u16*)(ws + 135266304);   // [4096][512]
    u16* QB   = (u16*)(ws + 139460608);   // [4096][512]
    float* CN = (float*)(ws + 143654912);
    u64* PACKED = (u64*)(ws + 143687680);
    double* PART = (double*)(ws + 143720448);

    const dim3 blk(256);

    // ---- precompute: bf16 conversions + weight transposes ----
    conv_pad_x<<<dim3(4096), blk, 0, stream>>>(x, xb);
    conv_bf16<<<dim3(2048), blk, 0, stream>>>(CB, CBB, 524288L);
    trans_bf16p<<<dim3(64, 626), dim3(32, 8), 0, stream>>>(W1, WT16, 20000, 2048, 20032);
    trans_bf16p<<<dim3(32, 64),  dim3(32, 8), 0, stream>>>(W2, WT2, 2048, 1024, 2048);
    trans_bf16p<<<dim3(16, 32),  dim3(32, 8), 0, stream>>>(W3, WT3, 1024, 512, 1024);
    trans_bf16p<<<dim3(32, 16),  dim3(32, 8), 0, stream>>>(W4, WT4, 512, 1024, 512);
    trans_bf16p<<<dim3(64, 32),  dim3(32, 8), 0, stream>>>(W5, WT5, 1024, 2048, 1024);
    cnorm_k<<<dim3(8192), dim3(64), 0, stream>>>(CB, CN);
    init_packed<<<dim3(16), blk, 0, stream>>>(PACKED);

    // ---- encoder ----
    // GEMM1: 256^2 tile, split-K over 4 chunks (8*16*4 = 512 blocks)
    gemm256<3><<<dim3(8, 16, 4), dim3(512), 131072, stream>>>(
        xb, WT16, nullptr, PART1, 4096, 2048, 20032, 20032, 20032);
    reduce_tanh4<<<dim3(4096), blk, 0, stream>>>(
        PART1, b1, ACT1, 1048576L, 2048, (size_t)4096 * 2048);
    // Wt1 dead; transpose W6 into the same arena (stream-ordered)
    trans_bf16p<<<dim3(625, 64), dim3(32, 8), 0, stream>>>(W6, WT16, 2048, 20000, 2048);
    mfma_gemm<1, 1, 0><<<dim3(8, 32), blk, 0, stream>>>(
        ACT1, WT2, b2, nullptr, ACT2, nullptr, 4096, 1024, 2048);
    mfma_gemm<1, 1, 1><<<dim3(4, 32), blk, 0, stream>>>(
        ACT2, WT3, b3, Z3F, Z3B, nullptr, 4096, 512, 1024);

    // ---- VQ: score GEMM with fused argmin, then gather + loss ----
    mfma_gemm<2, 0, 0><<<dim3(64, 32), blk, 0, stream>>>(
        Z3B, CBB, CN, nullptr, nullptr, PACKED, 4096, 8192, 512);
    quant_loss<<<dim3(2048), blk, 0, stream>>>(PACKED, CB, Z3F, qout, QB, PART);
    loss_final<<<dim3(1), blk, 0, stream>>>(PART, out);

    // ---- decoder ----
    mfma_gemm<1, 1, 0><<<dim3(8, 32), blk, 0, stream>>>(
        QB, WT4, b4, nullptr, ACT2, nullptr, 4096, 1024, 512);
    mfma_gemm<1, 1, 0><<<dim3(16, 32), blk, 0, stream>>>(
        ACT2, WT5, b5, nullptr, ACT1, nullptr, 4096, 2048, 1024);
    // GEMM6: 256^2 tile, grid 79x16 = 1264 blocks (padded Wt6 rows readable)
    gemm256<0><<<dim3(79, 16), dim3(512), 131072, stream>>>(
        ACT1, WT16, b6, xrec, 4096, 20000, 2048, 2048, 2048);
}